// Round 12
// baseline (699.446 us; speedup 1.0000x reference)
//
#include <hip/hip_runtime.h>

static constexpr int ND1=160, ND2=160, ND3=32;
static constexpr int SP  = ND1*ND2*ND3;        // 819200
static constexpr int CO  = 64;
static constexpr int OD1=80, OD2=80, OD3=32;
static constexpr int OSP = OD1*OD2*OD3;        // 204800
static constexpr int NSC = 64;                 // stat copies (contention spread)

typedef __attribute__((ext_vector_type(8))) short  short8;
typedef __attribute__((ext_vector_type(4))) float  f32x4;

__device__ __forceinline__ float b2f(unsigned u){ return __uint_as_float(u<<16); }
__device__ __forceinline__ unsigned short f2b(float f){
    unsigned u = __float_as_uint(f);
    u += 0x7fffu + ((u>>16)&1u);
    return (unsigned short)(u>>16);
}

// ---------------- mask dtype detection ----------------
__global__ void k_detect(const unsigned char* __restrict__ mb, int* __restrict__ flag)
{
    __shared__ int lf;
    if (threadIdx.x == 0) lf = 0;
    __syncthreads();
    int f = 0;
    for (int i = blockIdx.x*256 + threadIdx.x; i < SP; i += gridDim.x*256) {
        unsigned char b = mb[i];
        if (b > 1) f |= 4;
        if (b != 0 && (i & 3)) f |= 1;
    }
    if (f) atomicOr(&lf, f);
    __syncthreads();
    if (threadIdx.x == 0 && lf) atomicOr(flag, lf);
}

__global__ void k_mask(const void* __restrict__ mraw, const int* __restrict__ flag,
                       float* __restrict__ m, float* __restrict__ nactN)
{
    int i = blockIdx.x*256 + threadIdx.x;
    int f = *flag;
    float v;
    if (f & 4)      v = (reinterpret_cast<const float*>(mraw)[i] != 0.f) ? 1.f : 0.f;
    else if (f & 1) v = (reinterpret_cast<const unsigned char*>(mraw)[i] != 0) ? 1.f : 0.f;
    else            v = (reinterpret_cast<const int*>(mraw)[i] != 0) ? 1.f : 0.f;
    m[i] = v;
    float s = v;
    #pragma unroll
    for (int off = 32; off > 0; off >>= 1) s += __shfl_xor(s, off);
    __shared__ float wsum[4];
    if ((threadIdx.x & 63) == 0) wsum[threadIdx.x >> 6] = s;
    __syncthreads();
    if (threadIdx.x == 0) atomicAdd(&nactN[blockIdx.x & (NSC-1)], wsum[0]+wsum[1]+wsum[2]+wsum[3]);
}

__global__ void k_outmask(const float* __restrict__ m, float* __restrict__ om)
{
    int i = blockIdx.x*256 + threadIdx.x;   // < OSP
    int o3 = i & 31; int t = i >> 5; int o2 = t % OD2; int o1 = t / OD2;
    float s = 0.f;
    for (int kd = 0; kd < 3; kd++) { int d1 = 2*o1 - 1 + kd; if ((unsigned)d1 >= ND1) continue;
      for (int kh = 0; kh < 3; kh++) { int d2 = 2*o2 - 1 + kh; if ((unsigned)d2 >= ND2) continue;
        for (int kw = 0; kw < 3; kw++) { int d3 = o3 - 1 + kw; if ((unsigned)d3 >= ND3) continue;
          s += m[(d1*ND2 + d2)*ND3 + d3];
        } } }
    om[i] = (s > 0.f) ? 1.f : 0.f;
}

// ---------------- BN finalize (2 stages/launch) ----------------
__global__ void k_finalize2(const float* __restrict__ SN0, const float* __restrict__ g0,
                            const float* __restrict__ b0, float* __restrict__ o0,
                            const float* __restrict__ SN1, const float* __restrict__ g1,
                            const float* __restrict__ b1, float* __restrict__ o1,
                            const float* __restrict__ nactN)
{
    const float* SN = blockIdx.x ? SN1 : SN0;
    const float* g  = blockIdx.x ? g1  : g0;
    const float* b  = blockIdx.x ? b1  : b0;
    float*       o  = blockIdx.x ? o1  : o0;
    int c = threadIdx.x;
    float s1 = 0.f, s2 = 0.f;
    #pragma unroll 4
    for (int k = 0; k < NSC; k++){
        s1 += SN[k*128 + c];
        s2 += SN[k*128 + 64 + c];
    }
    float nn = nactN[c];
    #pragma unroll
    for (int off = 32; off > 0; off >>= 1) nn += __shfl_xor(nn, off);
    float mean = s1 / nn;
    float var  = s2 / nn - mean*mean;
    float inv  = rsqrtf(var + 1e-5f);
    float sc   = inv * g[c];
    o[c]      = sc;
    o[64 + c] = b[c] - mean*sc;
}

// ---------------- weight pre-pack ----------------
__global__ void k_wprep(const float* __restrict__ W, unsigned short* __restrict__ Wt,
                        int CIN, int NT)
{
    int i = blockIdx.x*256 + threadIdx.x;
    int K = CIN*NT;
    if (i >= 64*K) return;
    int ksub = i & 31;
    int t = i >> 5;
    int co = t & 63;
    int kc = t >> 6;
    int nch = CIN >> 5;
    int tap = kc / nch;
    int ci  = (kc - tap*nch)*32 + ksub;
    Wt[i] = f2b(W[((size_t)co*CIN + ci)*NT + tap]);
}

// ---------------- x f32 [ci][sp] -> masked bf16 [sp][32] ----------------
__global__ void k_prep_x(const float* __restrict__ x, const float* __restrict__ m,
                         unsigned short* __restrict__ xt)
{
    __shared__ float t[64][33];
    int sp0 = blockIdx.x*64;
    int tid = threadIdx.x;
    int c = tid>>6, s = tid&63;
    float mm = m[sp0+s];
    #pragma unroll
    for (int r=0;r<8;r++){
        int ci = c + r*4;
        t[s][ci] = x[(size_t)ci*SP + sp0 + s]*mm;
    }
    __syncthreads();
    int sp = tid>>2, c0 = (tid&3)*8;
    unsigned short o[8];
    #pragma unroll
    for (int i=0;i<8;i++) o[i] = f2b(t[sp][c0+i]);
    uint4 pk;
    pk.x = o[0] | ((unsigned)o[1]<<16);
    pk.y = o[2] | ((unsigned)o[3]<<16);
    pk.z = o[4] | ((unsigned)o[5]<<16);
    pk.w = o[6] | ((unsigned)o[7]<<16);
    *reinterpret_cast<uint4*>(xt + (size_t)(sp0+sp)*32 + c0) = pk;
}

// ---------------- res_B combine ----------------
__global__ void k_resB(const unsigned short* __restrict__ hA, const unsigned short* __restrict__ hB,
                       const float* __restrict__ sA, const float* __restrict__ sB,
                       const float* __restrict__ m,
                       unsigned short* __restrict__ rbt, float* __restrict__ resf)
{
    __shared__ float t[64][65];
    __shared__ float ss[256];
    int tid = threadIdx.x;
    if (tid < 128){ ss[tid] = sA[tid]; ss[128+tid] = sB[tid]; }
    __syncthreads();
    int sp0 = blockIdx.x*64;
    int sp = tid>>2, c0 = (tid&3)*16;
    float mm = m[sp0+sp];
    const size_t base = (size_t)(sp0+sp)*64 + c0;
    uint4 a0 = *reinterpret_cast<const uint4*>(hA + base);
    uint4 a1 = *reinterpret_cast<const uint4*>(hA + base + 8);
    uint4 b0 = *reinterpret_cast<const uint4*>(hB + base);
    uint4 b1 = *reinterpret_cast<const uint4*>(hB + base + 8);
    unsigned ua[16] = {a0.x&0xffffu,a0.x>>16,a0.y&0xffffu,a0.y>>16,a0.z&0xffffu,a0.z>>16,a0.w&0xffffu,a0.w>>16,
                       a1.x&0xffffu,a1.x>>16,a1.y&0xffffu,a1.y>>16,a1.z&0xffffu,a1.z>>16,a1.w&0xffffu,a1.w>>16};
    unsigned ub[16] = {b0.x&0xffffu,b0.x>>16,b0.y&0xffffu,b0.y>>16,b0.z&0xffffu,b0.z>>16,b0.w&0xffffu,b0.w>>16,
                       b1.x&0xffffu,b1.x>>16,b1.y&0xffffu,b1.y>>16,b1.z&0xffffu,b1.z>>16,b1.w&0xffffu,b1.w>>16};
    unsigned short o[16];
    #pragma unroll
    for (int q=0;q<16;q++){
        int ci = c0+q;
        float v = (b2f(ua[q])*ss[ci] + ss[64+ci] + b2f(ub[q])*ss[128+ci] + ss[192+ci])*mm;
        t[sp][ci] = v;
        o[q] = f2b(v);
    }
    uint4 p0, p1;
    p0.x = o[0]|((unsigned)o[1]<<16);  p0.y = o[2]|((unsigned)o[3]<<16);
    p0.z = o[4]|((unsigned)o[5]<<16);  p0.w = o[6]|((unsigned)o[7]<<16);
    p1.x = o[8]|((unsigned)o[9]<<16);  p1.y = o[10]|((unsigned)o[11]<<16);
    p1.z = o[12]|((unsigned)o[13]<<16); p1.w = o[14]|((unsigned)o[15]<<16);
    *reinterpret_cast<uint4*>(rbt + base)     = p0;
    *reinterpret_cast<uint4*>(rbt + base + 8) = p1;
    __syncthreads();
    int ci = tid>>2, s0 = (tid&3)*16;
    #pragma unroll
    for (int kq=0;kq<4;kq++){
        float4 ov;
        ov.x = t[s0+4*kq+0][ci]; ov.y = t[s0+4*kq+1][ci];
        ov.z = t[s0+4*kq+2][ci]; ov.w = t[s0+4*kq+3][ci];
        *reinterpret_cast<float4*>(resf + (size_t)ci*SP + sp0 + s0 + 4*kq) = ov;
    }
}

// ---------------- MFMA conv: weights in REGISTERS (round-11 winner, unchanged) ----------------
template<int KIND, int CIN, bool HASAFF>
__launch_bounds__(256, (CIN==32) ? 3 : 2)
__global__ void mconv10(const unsigned short* __restrict__ in,
                        const unsigned short* __restrict__ Wt,
                        const float* __restrict__ scsh,
                        const float* __restrict__ mstage,
                        const float* __restrict__ mout,
                        unsigned short* __restrict__ outb,
                        float* __restrict__ statsN)
{
    constexpr int NCH  = CIN/32;
    constexpr int NKC  = NCH*9;
    constexpr int NR   = 10;
    constexpr int ROWB = 34*CIN*2;
    constexpr int SWZ  = (CIN==64) ? 7 : 3;
    __shared__ __align__(16) char lds[NR*ROWB];
    __shared__ float sst[128];

    const int tid = threadIdx.x;
    const int w = tid>>6, l = tid&63, g = l>>4, lj = l&15;
    const int h = w&1, rg = w>>1;

    int gi = (blockIdx.x & 7)*(gridDim.x>>3) + (blockIdx.x>>3);
    int z  = gi % 160;
    int r0 = (gi / 160)*8;

    if (tid < 128) sst[tid] = 0.f;

    const int sd3 = tid>>3;
    const int k0  = (tid&7)*(CIN/8);

    float sc[8], sh[8];
    if (HASAFF){
        #pragma unroll
        for (int j=0;j<8;j++){ sc[j]=scsh[k0+j]; sh[j]=scsh[64+k0+j]; }
    }

    for (int i = tid; i < NR*2*(CIN/8); i += 256){
        int per = CIN/8;
        int rr = i / (2*per);
        int rem = i - rr*2*per;
        int slot = (rem >= per) ? 33 : 0;
        int kc16 = (rem >= per) ? (rem - per) : rem;
        int dst = rr*ROWB + slot*CIN*2 + kc16*16;
        dst ^= ((slot&SWZ)<<4);
        *reinterpret_cast<uint4*>(lds + dst) = make_uint4(0,0,0,0);
    }

    if (CIN==64){
        uint4 v[NR]; float mmr[NR];
        #pragma unroll
        for (int rr=0; rr<NR; rr++){
            int rw = r0 - 1 + rr;
            v[rr] = make_uint4(0,0,0,0); mmr[rr] = 0.f;
            if ((unsigned)rw < 160u){
                int vox = (KIND==0) ? ((rw*ND2 + z)*ND3 + sd3)
                                    : ((z*ND2 + rw)*ND3 + sd3);
                v[rr] = *reinterpret_cast<const uint4*>(in + (size_t)vox*CIN + k0);
                if (HASAFF) mmr[rr] = mstage[vox];
            }
        }
        #pragma unroll
        for (int rr=0; rr<NR; rr++){
            uint4 vv = v[rr];
            if (HASAFF){
                float mm = mmr[rr];
                unsigned us[8] = {vv.x&0xffffu,vv.x>>16,vv.y&0xffffu,vv.y>>16,
                                  vv.z&0xffffu,vv.z>>16,vv.w&0xffffu,vv.w>>16};
                unsigned short o[8];
                #pragma unroll
                for (int j=0;j<8;j++) o[j] = f2b((b2f(us[j])*sc[j]+sh[j])*mm);
                vv.x = o[0]|((unsigned)o[1]<<16); vv.y = o[2]|((unsigned)o[3]<<16);
                vv.z = o[4]|((unsigned)o[5]<<16); vv.w = o[6]|((unsigned)o[7]<<16);
            }
            int dst = (rr*ROWB + (((sd3+1)*CIN + k0)*2)) ^ (((sd3+1)&SWZ)<<4);
            *reinterpret_cast<uint4*>(lds + dst) = vv;
        }
    } else {
        uint2 v[NR];
        #pragma unroll
        for (int rr=0; rr<NR; rr++){
            int rw = r0 - 1 + rr;
            v[rr] = make_uint2(0,0);
            if ((unsigned)rw < 160u){
                int vox = (KIND==0) ? ((rw*ND2 + z)*ND3 + sd3)
                                    : ((z*ND2 + rw)*ND3 + sd3);
                v[rr] = *reinterpret_cast<const uint2*>(in + (size_t)vox*CIN + k0);
            }
        }
        #pragma unroll
        for (int rr=0; rr<NR; rr++){
            int dst = (rr*ROWB + (((sd3+1)*CIN + k0)*2)) ^ (((sd3+1)&SWZ)<<4);
            *reinterpret_cast<uint2*>(lds + dst) = v[rr];
        }
    }

    short8 pa[NKC][2];
    {
        const unsigned short* wb = Wt + (size_t)(h*32)*32 + lj*32 + g*8;
        #pragma unroll
        for (int kc=0; kc<NKC; kc++){
            pa[kc][0] = *reinterpret_cast<const short8*>(wb + (size_t)kc*2048);
            pa[kc][1] = *reinterpret_cast<const short8*>(wb + (size_t)kc*2048 + 512);
        }
    }

    int tb[8], ovox[8];
    float mm[8];
    #pragma unroll
    for (int t=0;t<8;t++){
        int rowb = rg*4 + (t>>1);
        int o3   = (t&1)*16 + lj;
        tb[t] = rowb*ROWB + ((o3*CIN + g*8)*2);
        int o2r = r0 + rowb;
        ovox[t] = (KIND==0) ? ((o2r*ND2 + z)*ND3 + o3)
                            : ((z*ND2 + o2r)*ND3 + o3);
        mm[t] = mout[ovox[t]];
    }
    int swz[3];
    #pragma unroll
    for (int kw=0;kw<3;kw++) swz[kw] = ((lj+kw)&SWZ)<<4;

    __syncthreads();

    f32x4 acc[2][8];
    #pragma unroll
    for (int c=0;c<2;c++)
        #pragma unroll
        for (int t=0;t<8;t++)
            #pragma unroll
            for (int q=0;q<4;q++) acc[c][t][q] = 0.f;

    #pragma unroll
    for (int ch=0; ch<NCH; ch++){
        #pragma unroll
        for (int tap=0; tap<9; tap++){
            const int kd = tap/3, kw = tap - kd*3;
            const int kc = tap*NCH + ch;
            const int tapoff = kd*ROWB + (kw*CIN + ch*32)*2;
            #pragma unroll
            for (int t=0;t<8;t++){
                int off = (tb[t] + tapoff) ^ swz[kw];
                short8 bv = *reinterpret_cast<const short8*>(lds + off);
                acc[0][t] = __builtin_amdgcn_mfma_f32_16x16x32_bf16(pa[kc][0], bv, acc[0][t], 0,0,0);
                acc[1][t] = __builtin_amdgcn_mfma_f32_16x16x32_bf16(pa[kc][1], bv, acc[1][t], 0,0,0);
            }
        }
    }

    #pragma unroll
    for (int c=0;c<2;c++){
        const int ct = h*2 + c;
        float s1[4] = {0.f,0.f,0.f,0.f};
        float s2[4] = {0.f,0.f,0.f,0.f};
        #pragma unroll
        for (int t=0;t<8;t++){
            float v[4];
            #pragma unroll
            for (int r=0;r<4;r++){
                float xv = acc[c][t][r]*mm[t];
                xv = (xv >= 0.f) ? xv : 0.01f*xv;
                v[r] = xv; s1[r] += xv; s2[r] += xv*xv;
            }
            unsigned lo = f2b(v[0]) | ((unsigned)f2b(v[1])<<16);
            unsigned hi = f2b(v[2]) | ((unsigned)f2b(v[3])<<16);
            *reinterpret_cast<uint2*>(outb + (size_t)ovox[t]*64 + ct*16 + g*4) = make_uint2(lo,hi);
        }
        #pragma unroll
        for (int r=0;r<4;r++){
            float a = s1[r], b = s2[r];
            a += __shfl_xor(a,1); b += __shfl_xor(b,1);
            a += __shfl_xor(a,2); b += __shfl_xor(b,2);
            a += __shfl_xor(a,4); b += __shfl_xor(b,4);
            a += __shfl_xor(a,8); b += __shfl_xor(b,8);
            if (lj == 0){
                atomicAdd(&sst[ct*16 + g*4 + r], a);
                atomicAdd(&sst[64 + ct*16 + g*4 + r], b);
            }
        }
    }
    __syncthreads();
    if (tid < 128){
        float* sg = statsN + (size_t)(blockIdx.x & (NSC-1))*128;
        atomicAdd(&sg[tid], sst[tid]);
    }
}

// ---------------- pool conv: weights in REGISTERS (per-kd residency) ----------------
// Wave w: co-half h=w&1, row-pair rg=w>>1 -> rows rg*2, rg*2+1; acc[2][4].
// Per kd: pa[18][2] preloaded (batched, in flight across barrier); inner = pure ds_read+MFMA.
__launch_bounds__(256, 2)
__global__ void mpool3(const unsigned short* __restrict__ in,   // bf16 [vox][64]
                       const unsigned short* __restrict__ Wt,   // bf16 [kc][64co][32k]
                       const float* __restrict__ mout,          // out_mask
                       float* __restrict__ outf)                // f32 [co][OSP]
{
    constexpr int ROWB = 34*64*2;
    __shared__ __align__(16) char lds[9*ROWB];

    const int tid = threadIdx.x;
    const int w = tid>>6, l = tid&63, g = l>>4, lj = l&15;
    const int h = w&1, rg = w>>1;

    int gi = (blockIdx.x & 7)*(gridDim.x>>3) + (blockIdx.x>>3);
    int z  = gi % OD1;
    int r0 = (gi / OD1)*4;

    const int sd3 = tid>>3;
    const int k0  = (tid&7)*8;

    int swz[3];
    #pragma unroll
    for (int kw=0;kw<3;kw++) swz[kw] = ((lj+kw)&7)<<4;

    // border zeros once (slots 0, 33)
    for (int i = tid; i < 9*2*8; i += 256){
        int rr = i / 16;
        int rem = i - rr*16;
        int slot = (rem >= 8) ? 33 : 0;
        int kc16 = rem & 7;
        int dst = rr*ROWB + slot*128 + kc16*16;
        dst ^= ((slot&7)<<4);
        *reinterpret_cast<uint4*>(lds + dst) = make_uint4(0,0,0,0);
    }

    // per-tile constants: 4 tiles (2 rows x 2 o3-halves)
    int tbl[4], ovx[4];
    float om[4];
    #pragma unroll
    for (int t=0;t<4;t++){
        int row = rg*2 + (t>>1);
        int o3  = (t&1)*16 + lj;
        tbl[t] = (o3*64 + g*8)*2;
        ovx[t] = (z*OD2 + (r0 + row))*OD3 + o3;
        om[t]  = mout[ovx[t]];
    }

    f32x4 acc[2][4];
    #pragma unroll
    for (int c=0;c<2;c++)
        #pragma unroll
        for (int t=0;t<4;t++)
            #pragma unroll
            for (int q=0;q<4;q++) acc[c][t][q] = 0.f;

    const unsigned short* wb = Wt + (size_t)(h*32)*32 + lj*32 + g*8;

    uint4 rv[9];
    short8 pa[18][2];

    #pragma unroll 1
    for (int kd=0; kd<3; kd++){
        // issue data-plane loads (latency spans the barrier)
        {
            int d1 = 2*z - 1 + kd;
            bool pok = ((unsigned)d1 < (unsigned)ND1);
            #pragma unroll
            for (int rr=0; rr<9; rr++){
                int d2 = 2*r0 - 1 + rr;
                rv[rr] = make_uint4(0,0,0,0);
                if (pok && ((unsigned)d2 < (unsigned)ND2)){
                    int vox = (d1*ND2 + d2)*ND3 + sd3;
                    rv[rr] = *reinterpret_cast<const uint4*>(in + (size_t)vox*64 + k0);
                }
            }
        }
        // issue weight preloads for this kd (18 kc, stays in VGPRs)
        #pragma unroll
        for (int i=0;i<18;i++){
            const int ch = i/9, tap = i - (i/9)*9;
            const int kc = (kd*9 + tap)*2 + ch;
            pa[i][0] = *reinterpret_cast<const short8*>(wb + (size_t)kc*2048);
            pa[i][1] = *reinterpret_cast<const short8*>(wb + (size_t)kc*2048 + 512);
        }
        __syncthreads();   // prev plane's compute done
        #pragma unroll
        for (int rr=0; rr<9; rr++){
            int dst = (rr*ROWB + (((sd3+1)*64 + k0)*2)) ^ (((sd3+1)&7)<<4);
            *reinterpret_cast<uint4*>(lds + dst) = rv[rr];
        }
        __syncthreads();
        // compute: pure ds_read + MFMA, zero global loads
        #pragma unroll
        for (int ch=0; ch<2; ch++){
            #pragma unroll
            for (int tap=0; tap<9; tap++){
                const int kh = tap/3, kw = tap - (tap/3)*3;
                const int pi = ch*9 + tap;
                #pragma unroll
                for (int t=0;t<4;t++){
                    const int rowl = 2*(rg*2 + (t>>1)) + kh;
                    int off = (rowl*ROWB + (kw*64 + ch*32)*2 + tbl[t]) ^ swz[kw];
                    short8 bv = *reinterpret_cast<const short8*>(lds + off);
                    acc[0][t] = __builtin_amdgcn_mfma_f32_16x16x32_bf16(pa[pi][0], bv, acc[0][t], 0,0,0);
                    acc[1][t] = __builtin_amdgcn_mfma_f32_16x16x32_bf16(pa[pi][1], bv, acc[1][t], 0,0,0);
                }
            }
        }
    }
    // epilogue
    #pragma unroll
    for (int c=0;c<2;c++){
        const int ct = h*2 + c;
        #pragma unroll
        for (int t=0;t<4;t++){
            #pragma unroll
            for (int r=0;r<4;r++){
                int co = ct*16 + g*4 + r;
                outf[(size_t)co*OSP + ovx[t]] = acc[c][t][r]*om[t];
            }
        }
    }
}

// ---------------- launch ----------------
extern "C" void kernel_launch(void* const* d_in, const int* in_sizes, int n_in,
                              void* d_out, int out_size, void* d_ws, size_t ws_size,
                              hipStream_t stream)
{
    const float* x      = (const float*)d_in[0];
    const void*  mraw   = d_in[1];
    const float* W_A1   = (const float*)d_in[2];
    const float* W_A2   = (const float*)d_in[3];
    const float* W_B1   = (const float*)d_in[4];
    const float* W_B2   = (const float*)d_in[5];
    const float* W_pool = (const float*)d_in[6];
    const float* g_A1 = (const float*)d_in[7],  *b_A1 = (const float*)d_in[8];
    const float* g_A2 = (const float*)d_in[9],  *b_A2 = (const float*)d_in[10];
    const float* g_B1 = (const float*)d_in[11], *b_B1 = (const float*)d_in[12];
    const float* g_B2 = (const float*)d_in[13], *b_B2 = (const float*)d_in[14];

    char* p = (char*)d_ws;
    float* m     = (float*)p; p += (size_t)SP*4;
    float* omask = (float*)p; p += (size_t)OSP*4;
    float* statsN= (float*)p; p += 4*NSC*128*4;
    float* scsh  = (float*)p; p += 4*128*4;
    float* nactN = (float*)p; p += NSC*4;
    int*   flag  = (int*)p;   p += 4;
    p += 252;
    unsigned short* WtA1 = (unsigned short*)p; p += 288*64*2;
    unsigned short* WtA2 = (unsigned short*)p; p += 576*64*2;
    unsigned short* WtB1 = (unsigned short*)p; p += 288*64*2;
    unsigned short* WtB2 = (unsigned short*)p; p += 576*64*2;
    unsigned short* WtP  = (unsigned short*)p; p += 1728*64*2;
    unsigned short* X = (unsigned short*)p; p += (size_t)SP*32*2;
    unsigned short* P = (unsigned short*)p; p += (size_t)SP*64*2;
    unsigned short* Q = (unsigned short*)p; p += (size_t)SP*64*2;
    unsigned short* R = (unsigned short*)p; p += (size_t)SP*64*2;

    float* down = (float*)d_out;                 // [64][OSP]
    float* resf = down + (size_t)CO*OSP;         // [64][SP]

    hipMemsetAsync(statsN, 0, (4*NSC*128 + 4*128 + NSC)*4 + 4, stream);
    k_detect<<<256, 256, 0, stream>>>((const unsigned char*)mraw, flag);
    k_mask<<<SP/256, 256, 0, stream>>>(mraw, flag, m, nactN);
    k_outmask<<<OSP/256, 256, 0, stream>>>(m, omask);
    k_prep_x<<<SP/64, 256, 0, stream>>>(x, m, X);

    k_wprep<<<(64*288+255)/256, 256, 0, stream>>>(W_A1, WtA1, 32, 9);
    k_wprep<<<(64*576+255)/256, 256, 0, stream>>>(W_A2, WtA2, 64, 9);
    k_wprep<<<(64*288+255)/256, 256, 0, stream>>>(W_B1, WtB1, 32, 9);
    k_wprep<<<(64*576+255)/256, 256, 0, stream>>>(W_B2, WtB2, 64, 9);
    k_wprep<<<(64*1728+255)/256, 256, 0, stream>>>(W_pool, WtP, 64, 27);

    float* SA1 = statsN + 0*NSC*128;
    float* SA2 = statsN + 1*NSC*128;
    float* SB1 = statsN + 2*NSC*128;
    float* SB2 = statsN + 3*NSC*128;

    // stage 1: A1 and B1 (both read X)
    mconv10<0,32,false><<<3200, 256, 0, stream>>>(X, WtA1, nullptr, nullptr, m, P, SA1);
    mconv10<1,32,false><<<3200, 256, 0, stream>>>(X, WtB1, nullptr, nullptr, m, Q, SB1);
    k_finalize2<<<2, 64, 0, stream>>>(SA1, g_A1, b_A1, scsh + 0,
                                      SB1, g_B1, b_B1, scsh + 256, nactN);
    // stage 2: A2 on BN_A1(P), B2 on BN_B1(Q) (affine fused in staging)
    mconv10<1,64,true><<<3200, 256, 0, stream>>>(P, WtA2, scsh + 0,   m, m, R, SA2);
    mconv10<0,64,true><<<3200, 256, 0, stream>>>(Q, WtB2, scsh + 256, m, m, P, SB2);
    k_finalize2<<<2, 64, 0, stream>>>(SA2, g_A2, b_A2, scsh + 128,
                                      SB2, g_B2, b_B2, scsh + 384, nactN);
    // res_B combine -> Q (bf16 for pool) + resf (f32 output)
    k_resB<<<SP/64, 256, 0, stream>>>(R, P, scsh + 128, scsh + 384, m, Q, resf);
    // pool
    mpool3<<<1600, 256, 0, stream>>>(Q, WtP, omask, down);
}

// Round 13
// 667.772 us; speedup vs baseline: 1.0474x; 1.0474x over previous
//
#include <hip/hip_runtime.h>

static constexpr int ND1=160, ND2=160, ND3=32;
static constexpr int SP  = ND1*ND2*ND3;        // 819200
static constexpr int CO  = 64;
static constexpr int OD1=80, OD2=80, OD3=32;
static constexpr int OSP = OD1*OD2*OD3;        // 204800
static constexpr int NSC = 64;                 // stat copies (contention spread)

typedef __attribute__((ext_vector_type(8))) short  short8;
typedef __attribute__((ext_vector_type(4))) float  f32x4;

__device__ __forceinline__ float b2f(unsigned u){ return __uint_as_float(u<<16); }
__device__ __forceinline__ unsigned short f2b(float f){
    unsigned u = __float_as_uint(f);
    u += 0x7fffu + ((u>>16)&1u);
    return (unsigned short)(u>>16);
}

// ---------------- mask dtype detection ----------------
__global__ void k_detect(const unsigned char* __restrict__ mb, int* __restrict__ flag)
{
    __shared__ int lf;
    if (threadIdx.x == 0) lf = 0;
    __syncthreads();
    int f = 0;
    for (int i = blockIdx.x*256 + threadIdx.x; i < SP; i += gridDim.x*256) {
        unsigned char b = mb[i];
        if (b > 1) f |= 4;
        if (b != 0 && (i & 3)) f |= 1;
    }
    if (f) atomicOr(&lf, f);
    __syncthreads();
    if (threadIdx.x == 0 && lf) atomicOr(flag, lf);
}

__global__ void k_mask(const void* __restrict__ mraw, const int* __restrict__ flag,
                       float* __restrict__ m, float* __restrict__ nactN)
{
    int i = blockIdx.x*256 + threadIdx.x;
    int f = *flag;
    float v;
    if (f & 4)      v = (reinterpret_cast<const float*>(mraw)[i] != 0.f) ? 1.f : 0.f;
    else if (f & 1) v = (reinterpret_cast<const unsigned char*>(mraw)[i] != 0) ? 1.f : 0.f;
    else            v = (reinterpret_cast<const int*>(mraw)[i] != 0) ? 1.f : 0.f;
    m[i] = v;
    float s = v;
    #pragma unroll
    for (int off = 32; off > 0; off >>= 1) s += __shfl_xor(s, off);
    __shared__ float wsum[4];
    if ((threadIdx.x & 63) == 0) wsum[threadIdx.x >> 6] = s;
    __syncthreads();
    if (threadIdx.x == 0) atomicAdd(&nactN[blockIdx.x & (NSC-1)], wsum[0]+wsum[1]+wsum[2]+wsum[3]);
}

__global__ void k_outmask(const float* __restrict__ m, float* __restrict__ om)
{
    int i = blockIdx.x*256 + threadIdx.x;   // < OSP
    int o3 = i & 31; int t = i >> 5; int o2 = t % OD2; int o1 = t / OD2;
    float s = 0.f;
    for (int kd = 0; kd < 3; kd++) { int d1 = 2*o1 - 1 + kd; if ((unsigned)d1 >= ND1) continue;
      for (int kh = 0; kh < 3; kh++) { int d2 = 2*o2 - 1 + kh; if ((unsigned)d2 >= ND2) continue;
        for (int kw = 0; kw < 3; kw++) { int d3 = o3 - 1 + kw; if ((unsigned)d3 >= ND3) continue;
          s += m[(d1*ND2 + d2)*ND3 + d3];
        } } }
    om[i] = (s > 0.f) ? 1.f : 0.f;
}

// ---------------- BN finalize (2 stages/launch) ----------------
__global__ void k_finalize2(const float* __restrict__ SN0, const float* __restrict__ g0,
                            const float* __restrict__ b0, float* __restrict__ o0,
                            const float* __restrict__ SN1, const float* __restrict__ g1,
                            const float* __restrict__ b1, float* __restrict__ o1,
                            const float* __restrict__ nactN)
{
    const float* SN = blockIdx.x ? SN1 : SN0;
    const float* g  = blockIdx.x ? g1  : g0;
    const float* b  = blockIdx.x ? b1  : b0;
    float*       o  = blockIdx.x ? o1  : o0;
    int c = threadIdx.x;
    float s1 = 0.f, s2 = 0.f;
    #pragma unroll 4
    for (int k = 0; k < NSC; k++){
        s1 += SN[k*128 + c];
        s2 += SN[k*128 + 64 + c];
    }
    float nn = nactN[c];
    #pragma unroll
    for (int off = 32; off > 0; off >>= 1) nn += __shfl_xor(nn, off);
    float mean = s1 / nn;
    float var  = s2 / nn - mean*mean;
    float inv  = rsqrtf(var + 1e-5f);
    float sc   = inv * g[c];
    o[c]      = sc;
    o[64 + c] = b[c] - mean*sc;
}

// ---------------- weight pre-pack ----------------
__global__ void k_wprep(const float* __restrict__ W, unsigned short* __restrict__ Wt,
                        int CIN, int NT)
{
    int i = blockIdx.x*256 + threadIdx.x;
    int K = CIN*NT;
    if (i >= 64*K) return;
    int ksub = i & 31;
    int t = i >> 5;
    int co = t & 63;
    int kc = t >> 6;
    int nch = CIN >> 5;
    int tap = kc / nch;
    int ci  = (kc - tap*nch)*32 + ksub;
    Wt[i] = f2b(W[((size_t)co*CIN + ci)*NT + tap]);
}

// ---------------- x f32 [ci][sp] -> masked bf16 [sp][32] ----------------
__global__ void k_prep_x(const float* __restrict__ x, const float* __restrict__ m,
                         unsigned short* __restrict__ xt)
{
    __shared__ float t[64][33];
    int sp0 = blockIdx.x*64;
    int tid = threadIdx.x;
    int c = tid>>6, s = tid&63;
    float mm = m[sp0+s];
    #pragma unroll
    for (int r=0;r<8;r++){
        int ci = c + r*4;
        t[s][ci] = x[(size_t)ci*SP + sp0 + s]*mm;
    }
    __syncthreads();
    int sp = tid>>2, c0 = (tid&3)*8;
    unsigned short o[8];
    #pragma unroll
    for (int i=0;i<8;i++) o[i] = f2b(t[sp][c0+i]);
    uint4 pk;
    pk.x = o[0] | ((unsigned)o[1]<<16);
    pk.y = o[2] | ((unsigned)o[3]<<16);
    pk.z = o[4] | ((unsigned)o[5]<<16);
    pk.w = o[6] | ((unsigned)o[7]<<16);
    *reinterpret_cast<uint4*>(xt + (size_t)(sp0+sp)*32 + c0) = pk;
}

// ---------------- res_B combine ----------------
__global__ void k_resB(const unsigned short* __restrict__ hA, const unsigned short* __restrict__ hB,
                       const float* __restrict__ sA, const float* __restrict__ sB,
                       const float* __restrict__ m,
                       unsigned short* __restrict__ rbt, float* __restrict__ resf)
{
    __shared__ float t[64][65];
    __shared__ float ss[256];
    int tid = threadIdx.x;
    if (tid < 128){ ss[tid] = sA[tid]; ss[128+tid] = sB[tid]; }
    __syncthreads();
    int sp0 = blockIdx.x*64;
    int sp = tid>>2, c0 = (tid&3)*16;
    float mm = m[sp0+sp];
    const size_t base = (size_t)(sp0+sp)*64 + c0;
    uint4 a0 = *reinterpret_cast<const uint4*>(hA + base);
    uint4 a1 = *reinterpret_cast<const uint4*>(hA + base + 8);
    uint4 b0 = *reinterpret_cast<const uint4*>(hB + base);
    uint4 b1 = *reinterpret_cast<const uint4*>(hB + base + 8);
    unsigned ua[16] = {a0.x&0xffffu,a0.x>>16,a0.y&0xffffu,a0.y>>16,a0.z&0xffffu,a0.z>>16,a0.w&0xffffu,a0.w>>16,
                       a1.x&0xffffu,a1.x>>16,a1.y&0xffffu,a1.y>>16,a1.z&0xffffu,a1.z>>16,a1.w&0xffffu,a1.w>>16};
    unsigned ub[16] = {b0.x&0xffffu,b0.x>>16,b0.y&0xffffu,b0.y>>16,b0.z&0xffffu,b0.z>>16,b0.w&0xffffu,b0.w>>16,
                       b1.x&0xffffu,b1.x>>16,b1.y&0xffffu,b1.y>>16,b1.z&0xffffu,b1.z>>16,b1.w&0xffffu,b1.w>>16};
    unsigned short o[16];
    #pragma unroll
    for (int q=0;q<16;q++){
        int ci = c0+q;
        float v = (b2f(ua[q])*ss[ci] + ss[64+ci] + b2f(ub[q])*ss[128+ci] + ss[192+ci])*mm;
        t[sp][ci] = v;
        o[q] = f2b(v);
    }
    uint4 p0, p1;
    p0.x = o[0]|((unsigned)o[1]<<16);  p0.y = o[2]|((unsigned)o[3]<<16);
    p0.z = o[4]|((unsigned)o[5]<<16);  p0.w = o[6]|((unsigned)o[7]<<16);
    p1.x = o[8]|((unsigned)o[9]<<16);  p1.y = o[10]|((unsigned)o[11]<<16);
    p1.z = o[12]|((unsigned)o[13]<<16); p1.w = o[14]|((unsigned)o[15]<<16);
    *reinterpret_cast<uint4*>(rbt + base)     = p0;
    *reinterpret_cast<uint4*>(rbt + base + 8) = p1;
    __syncthreads();
    int ci = tid>>2, s0 = (tid&3)*16;
    #pragma unroll
    for (int kq=0;kq<4;kq++){
        float4 ov;
        ov.x = t[s0+4*kq+0][ci]; ov.y = t[s0+4*kq+1][ci];
        ov.z = t[s0+4*kq+2][ci]; ov.w = t[s0+4*kq+3][ci];
        *reinterpret_cast<float4*>(resf + (size_t)ci*SP + sp0 + s0 + 4*kq) = ov;
    }
}

// ---------------- MFMA conv: weights in REGISTERS (round-11 winner, unchanged) ----------------
template<int KIND, int CIN, bool HASAFF>
__launch_bounds__(256, (CIN==32) ? 3 : 2)
__global__ void mconv10(const unsigned short* __restrict__ in,
                        const unsigned short* __restrict__ Wt,
                        const float* __restrict__ scsh,
                        const float* __restrict__ mstage,
                        const float* __restrict__ mout,
                        unsigned short* __restrict__ outb,
                        float* __restrict__ statsN)
{
    constexpr int NCH  = CIN/32;
    constexpr int NKC  = NCH*9;
    constexpr int NR   = 10;
    constexpr int ROWB = 34*CIN*2;
    constexpr int SWZ  = (CIN==64) ? 7 : 3;
    __shared__ __align__(16) char lds[NR*ROWB];
    __shared__ float sst[128];

    const int tid = threadIdx.x;
    const int w = tid>>6, l = tid&63, g = l>>4, lj = l&15;
    const int h = w&1, rg = w>>1;

    int gi = (blockIdx.x & 7)*(gridDim.x>>3) + (blockIdx.x>>3);
    int z  = gi % 160;
    int r0 = (gi / 160)*8;

    if (tid < 128) sst[tid] = 0.f;

    const int sd3 = tid>>3;
    const int k0  = (tid&7)*(CIN/8);

    float sc[8], sh[8];
    if (HASAFF){
        #pragma unroll
        for (int j=0;j<8;j++){ sc[j]=scsh[k0+j]; sh[j]=scsh[64+k0+j]; }
    }

    for (int i = tid; i < NR*2*(CIN/8); i += 256){
        int per = CIN/8;
        int rr = i / (2*per);
        int rem = i - rr*2*per;
        int slot = (rem >= per) ? 33 : 0;
        int kc16 = (rem >= per) ? (rem - per) : rem;
        int dst = rr*ROWB + slot*CIN*2 + kc16*16;
        dst ^= ((slot&SWZ)<<4);
        *reinterpret_cast<uint4*>(lds + dst) = make_uint4(0,0,0,0);
    }

    if (CIN==64){
        uint4 v[NR]; float mmr[NR];
        #pragma unroll
        for (int rr=0; rr<NR; rr++){
            int rw = r0 - 1 + rr;
            v[rr] = make_uint4(0,0,0,0); mmr[rr] = 0.f;
            if ((unsigned)rw < 160u){
                int vox = (KIND==0) ? ((rw*ND2 + z)*ND3 + sd3)
                                    : ((z*ND2 + rw)*ND3 + sd3);
                v[rr] = *reinterpret_cast<const uint4*>(in + (size_t)vox*CIN + k0);
                if (HASAFF) mmr[rr] = mstage[vox];
            }
        }
        #pragma unroll
        for (int rr=0; rr<NR; rr++){
            uint4 vv = v[rr];
            if (HASAFF){
                float mm = mmr[rr];
                unsigned us[8] = {vv.x&0xffffu,vv.x>>16,vv.y&0xffffu,vv.y>>16,
                                  vv.z&0xffffu,vv.z>>16,vv.w&0xffffu,vv.w>>16};
                unsigned short o[8];
                #pragma unroll
                for (int j=0;j<8;j++) o[j] = f2b((b2f(us[j])*sc[j]+sh[j])*mm);
                vv.x = o[0]|((unsigned)o[1]<<16); vv.y = o[2]|((unsigned)o[3]<<16);
                vv.z = o[4]|((unsigned)o[5]<<16); vv.w = o[6]|((unsigned)o[7]<<16);
            }
            int dst = (rr*ROWB + (((sd3+1)*CIN + k0)*2)) ^ (((sd3+1)&SWZ)<<4);
            *reinterpret_cast<uint4*>(lds + dst) = vv;
        }
    } else {
        uint2 v[NR];
        #pragma unroll
        for (int rr=0; rr<NR; rr++){
            int rw = r0 - 1 + rr;
            v[rr] = make_uint2(0,0);
            if ((unsigned)rw < 160u){
                int vox = (KIND==0) ? ((rw*ND2 + z)*ND3 + sd3)
                                    : ((z*ND2 + rw)*ND3 + sd3);
                v[rr] = *reinterpret_cast<const uint2*>(in + (size_t)vox*CIN + k0);
            }
        }
        #pragma unroll
        for (int rr=0; rr<NR; rr++){
            int dst = (rr*ROWB + (((sd3+1)*CIN + k0)*2)) ^ (((sd3+1)&SWZ)<<4);
            *reinterpret_cast<uint2*>(lds + dst) = v[rr];
        }
    }

    short8 pa[NKC][2];
    {
        const unsigned short* wb = Wt + (size_t)(h*32)*32 + lj*32 + g*8;
        #pragma unroll
        for (int kc=0; kc<NKC; kc++){
            pa[kc][0] = *reinterpret_cast<const short8*>(wb + (size_t)kc*2048);
            pa[kc][1] = *reinterpret_cast<const short8*>(wb + (size_t)kc*2048 + 512);
        }
    }

    int tb[8], ovox[8];
    float mm[8];
    #pragma unroll
    for (int t=0;t<8;t++){
        int rowb = rg*4 + (t>>1);
        int o3   = (t&1)*16 + lj;
        tb[t] = rowb*ROWB + ((o3*CIN + g*8)*2);
        int o2r = r0 + rowb;
        ovox[t] = (KIND==0) ? ((o2r*ND2 + z)*ND3 + o3)
                            : ((z*ND2 + o2r)*ND3 + o3);
        mm[t] = mout[ovox[t]];
    }
    int swz[3];
    #pragma unroll
    for (int kw=0;kw<3;kw++) swz[kw] = ((lj+kw)&SWZ)<<4;

    __syncthreads();

    f32x4 acc[2][8];
    #pragma unroll
    for (int c=0;c<2;c++)
        #pragma unroll
        for (int t=0;t<8;t++)
            #pragma unroll
            for (int q=0;q<4;q++) acc[c][t][q] = 0.f;

    #pragma unroll
    for (int ch=0; ch<NCH; ch++){
        #pragma unroll
        for (int tap=0; tap<9; tap++){
            const int kd = tap/3, kw = tap - kd*3;
            const int kc = tap*NCH + ch;
            const int tapoff = kd*ROWB + (kw*CIN + ch*32)*2;
            #pragma unroll
            for (int t=0;t<8;t++){
                int off = (tb[t] + tapoff) ^ swz[kw];
                short8 bv = *reinterpret_cast<const short8*>(lds + off);
                acc[0][t] = __builtin_amdgcn_mfma_f32_16x16x32_bf16(pa[kc][0], bv, acc[0][t], 0,0,0);
                acc[1][t] = __builtin_amdgcn_mfma_f32_16x16x32_bf16(pa[kc][1], bv, acc[1][t], 0,0,0);
            }
        }
    }

    #pragma unroll
    for (int c=0;c<2;c++){
        const int ct = h*2 + c;
        float s1[4] = {0.f,0.f,0.f,0.f};
        float s2[4] = {0.f,0.f,0.f,0.f};
        #pragma unroll
        for (int t=0;t<8;t++){
            float v[4];
            #pragma unroll
            for (int r=0;r<4;r++){
                float xv = acc[c][t][r]*mm[t];
                xv = (xv >= 0.f) ? xv : 0.01f*xv;
                v[r] = xv; s1[r] += xv; s2[r] += xv*xv;
            }
            unsigned lo = f2b(v[0]) | ((unsigned)f2b(v[1])<<16);
            unsigned hi = f2b(v[2]) | ((unsigned)f2b(v[3])<<16);
            *reinterpret_cast<uint2*>(outb + (size_t)ovox[t]*64 + ct*16 + g*4) = make_uint2(lo,hi);
        }
        #pragma unroll
        for (int r=0;r<4;r++){
            float a = s1[r], b = s2[r];
            a += __shfl_xor(a,1); b += __shfl_xor(b,1);
            a += __shfl_xor(a,2); b += __shfl_xor(b,2);
            a += __shfl_xor(a,4); b += __shfl_xor(b,4);
            a += __shfl_xor(a,8); b += __shfl_xor(b,8);
            if (lj == 0){
                atomicAdd(&sst[ct*16 + g*4 + r], a);
                atomicAdd(&sst[64 + ct*16 + g*4 + r], b);
            }
        }
    }
    __syncthreads();
    if (tid < 128){
        float* sg = statsN + (size_t)(blockIdx.x & (NSC-1))*128;
        atomicAdd(&sg[tid], sst[tid]);
    }
}

// ---------------- pool conv: ch-phase staging, pad-80 rows, pa[9][2] per (ph,kd) ----------------
// LDS: 27 rows (3 kd-planes x 9 d2-rows) x 34 slots x 80 B (32ch + 16B pad) = 73440 B (dynamic).
// Wave w: co-half h=w&1, row-pair rg=w>>1; acc[2][4]. Inner: per tap 4 ds_read + 8 MFMA.
__launch_bounds__(256, 2)
__global__ void mpool4(const unsigned short* __restrict__ in,   // bf16 [vox][64]
                       const unsigned short* __restrict__ Wt,   // bf16 [kc][64co][32k]
                       const float* __restrict__ mout,          // out_mask
                       float* __restrict__ outf)                // f32 [co][OSP]
{
    constexpr int SLOTB = 80;          // 32ch*2B + 16B pad -> conflict-free by stride
    constexpr int ROWB  = 34*SLOTB;    // 2720
    extern __shared__ __align__(16) char lds[];   // 27*ROWB = 73440

    const int tid = threadIdx.x;
    const int w = tid>>6, l = tid&63, g = l>>4, lj = l&15;
    const int h = w&1, rg = w>>1;

    int gi = (blockIdx.x & 7)*(gridDim.x>>3) + (blockIdx.x>>3);
    int z  = gi % OD1;
    int r0 = (gi / OD1)*4;

    const int sd3 = tid>>3;            // 0..31
    const int kq  = tid&7;             // 4-ch chunk (8B)

    // border zeros: slots 0 and 33, all 27 rows (64B each)
    for (int i = tid; i < 27*2*4; i += 256){
        int row = i >> 3, rem = i & 7;
        int slot = (rem >= 4) ? 33 : 0;
        int c16 = rem & 3;
        *reinterpret_cast<uint4*>(lds + row*ROWB + slot*SLOTB + c16*16) = make_uint4(0,0,0,0);
    }

    // per-tile constants: 4 tiles (2 rows x 2 o3-halves)
    int ovx[4];
    float om[4];
    #pragma unroll
    for (int t=0;t<4;t++){
        int row = rg*2 + (t>>1);
        int o3  = (t&1)*16 + lj;
        ovx[t] = (z*OD2 + (r0 + row))*OD3 + o3;
        om[t]  = mout[ovx[t]];
    }

    f32x4 acc[2][4];
    #pragma unroll
    for (int c=0;c<2;c++)
        #pragma unroll
        for (int t=0;t<4;t++)
            #pragma unroll
            for (int q=0;q<4;q++) acc[c][t][q] = 0.f;

    const unsigned short* wbase = Wt + (size_t)(h*32)*32 + lj*32 + g*8;

    #pragma unroll 1
    for (int ph=0; ph<2; ph++){
        // ---- issue all 27 row-loads (in flight across the barrier) ----
        uint2 v[27];
        #pragma unroll
        for (int i=0;i<27;i++){
            const int kd = i/9, rr = i - (i/9)*9;
            int d1 = 2*z - 1 + kd;
            int d2 = 2*r0 - 1 + rr;
            v[i] = make_uint2(0,0);
            if ((unsigned)d1 < (unsigned)ND1 && (unsigned)d2 < (unsigned)ND2){
                int vox = (d1*ND2 + d2)*ND3 + sd3;
                v[i] = *reinterpret_cast<const uint2*>(in + (size_t)vox*64 + ph*32 + kq*4);
            }
        }
        __syncthreads();    // ph>0: prev phase compute done; ph==0: border zeros visible
        #pragma unroll
        for (int i=0;i<27;i++){
            *reinterpret_cast<uint2*>(lds + i*ROWB + (sd3+1)*SLOTB + kq*8) = v[i];
        }
        __syncthreads();

        // ---- compute: 3 kd, weights per (ph,kd) in registers ----
        #pragma unroll
        for (int kd=0; kd<3; kd++){
            short8 pa[9][2];
            #pragma unroll
            for (int tap=0; tap<9; tap++){
                const int kc = (kd*9 + tap)*2 + ph;
                pa[tap][0] = *reinterpret_cast<const short8*>(wbase + (size_t)kc*2048);
                pa[tap][1] = *reinterpret_cast<const short8*>(wbase + (size_t)kc*2048 + 512);
            }
            #pragma unroll
            for (int tap=0; tap<9; tap++){
                const int kh = tap/3, kw = tap - (tap/3)*3;
                #pragma unroll
                for (int t=0;t<4;t++){
                    const int rr = 2*(rg*2 + (t>>1)) + kh;      // 0..8
                    const int slot = (t&1)*16 + lj + kw;        // 0..33
                    const char* bp = lds + (kd*9 + rr)*ROWB + slot*SLOTB + g*16;
                    short8 bv = *reinterpret_cast<const short8*>(bp);
                    acc[0][t] = __builtin_amdgcn_mfma_f32_16x16x32_bf16(pa[tap][0], bv, acc[0][t], 0,0,0);
                    acc[1][t] = __builtin_amdgcn_mfma_f32_16x16x32_bf16(pa[tap][1], bv, acc[1][t], 0,0,0);
                }
            }
        }
    }

    // ---- epilogue ----
    #pragma unroll
    for (int c=0;c<2;c++){
        const int ct = h*2 + c;
        #pragma unroll
        for (int t=0;t<4;t++){
            #pragma unroll
            for (int r=0;r<4;r++){
                int co = ct*16 + g*4 + r;
                outf[(size_t)co*OSP + ovx[t]] = acc[c][t][r]*om[t];
            }
        }
    }
}

// ---------------- launch ----------------
extern "C" void kernel_launch(void* const* d_in, const int* in_sizes, int n_in,
                              void* d_out, int out_size, void* d_ws, size_t ws_size,
                              hipStream_t stream)
{
    const float* x      = (const float*)d_in[0];
    const void*  mraw   = d_in[1];
    const float* W_A1   = (const float*)d_in[2];
    const float* W_A2   = (const float*)d_in[3];
    const float* W_B1   = (const float*)d_in[4];
    const float* W_B2   = (const float*)d_in[5];
    const float* W_pool = (const float*)d_in[6];
    const float* g_A1 = (const float*)d_in[7],  *b_A1 = (const float*)d_in[8];
    const float* g_A2 = (const float*)d_in[9],  *b_A2 = (const float*)d_in[10];
    const float* g_B1 = (const float*)d_in[11], *b_B1 = (const float*)d_in[12];
    const float* g_B2 = (const float*)d_in[13], *b_B2 = (const float*)d_in[14];

    char* p = (char*)d_ws;
    float* m     = (float*)p; p += (size_t)SP*4;
    float* omask = (float*)p; p += (size_t)OSP*4;
    float* statsN= (float*)p; p += 4*NSC*128*4;
    float* scsh  = (float*)p; p += 4*128*4;
    float* nactN = (float*)p; p += NSC*4;
    int*   flag  = (int*)p;   p += 4;
    p += 252;
    unsigned short* WtA1 = (unsigned short*)p; p += 288*64*2;
    unsigned short* WtA2 = (unsigned short*)p; p += 576*64*2;
    unsigned short* WtB1 = (unsigned short*)p; p += 288*64*2;
    unsigned short* WtB2 = (unsigned short*)p; p += 576*64*2;
    unsigned short* WtP  = (unsigned short*)p; p += 1728*64*2;
    unsigned short* X = (unsigned short*)p; p += (size_t)SP*32*2;
    unsigned short* P = (unsigned short*)p; p += (size_t)SP*64*2;
    unsigned short* Q = (unsigned short*)p; p += (size_t)SP*64*2;
    unsigned short* R = (unsigned short*)p; p += (size_t)SP*64*2;

    float* down = (float*)d_out;                 // [64][OSP]
    float* resf = down + (size_t)CO*OSP;         // [64][SP]

    const int shmP = 27*34*80;                   // 73440
    hipFuncSetAttribute((const void*)&mpool4, hipFuncAttributeMaxDynamicSharedMemorySize, shmP);

    hipMemsetAsync(statsN, 0, (4*NSC*128 + 4*128 + NSC)*4 + 4, stream);
    k_detect<<<256, 256, 0, stream>>>((const unsigned char*)mraw, flag);
    k_mask<<<SP/256, 256, 0, stream>>>(mraw, flag, m, nactN);
    k_outmask<<<OSP/256, 256, 0, stream>>>(m, omask);
    k_prep_x<<<SP/64, 256, 0, stream>>>(x, m, X);

    k_wprep<<<(64*288+255)/256, 256, 0, stream>>>(W_A1, WtA1, 32, 9);
    k_wprep<<<(64*576+255)/256, 256, 0, stream>>>(W_A2, WtA2, 64, 9);
    k_wprep<<<(64*288+255)/256, 256, 0, stream>>>(W_B1, WtB1, 32, 9);
    k_wprep<<<(64*576+255)/256, 256, 0, stream>>>(W_B2, WtB2, 64, 9);
    k_wprep<<<(64*1728+255)/256, 256, 0, stream>>>(W_pool, WtP, 64, 27);

    float* SA1 = statsN + 0*NSC*128;
    float* SA2 = statsN + 1*NSC*128;
    float* SB1 = statsN + 2*NSC*128;
    float* SB2 = statsN + 3*NSC*128;

    // stage 1: A1 and B1 (both read X)
    mconv10<0,32,false><<<3200, 256, 0, stream>>>(X, WtA1, nullptr, nullptr, m, P, SA1);
    mconv10<1,32,false><<<3200, 256, 0, stream>>>(X, WtB1, nullptr, nullptr, m, Q, SB1);
    k_finalize2<<<2, 64, 0, stream>>>(SA1, g_A1, b_A1, scsh + 0,
                                      SB1, g_B1, b_B1, scsh + 256, nactN);
    // stage 2: A2 on BN_A1(P), B2 on BN_B1(Q) (affine fused in staging)
    mconv10<1,64,true><<<3200, 256, 0, stream>>>(P, WtA2, scsh + 0,   m, m, R, SA2);
    mconv10<0,64,true><<<3200, 256, 0, stream>>>(Q, WtB2, scsh + 256, m, m, P, SB2);
    k_finalize2<<<2, 64, 0, stream>>>(SA2, g_A2, b_A2, scsh + 128,
                                      SB2, g_B2, b_B2, scsh + 384, nactN);
    // res_B combine -> Q (bf16 for pool) + resf (f32 output)
    k_resB<<<SP/64, 256, 0, stream>>>(R, P, scsh + 128, scsh + 384, m, Q, resf);
    // pool
    mpool4<<<1600, 256, shmP, stream>>>(Q, WtP, omask, down);
}

// Round 14
// 638.696 us; speedup vs baseline: 1.0951x; 1.0455x over previous
//
#include <hip/hip_runtime.h>

static constexpr int ND1=160, ND2=160, ND3=32;
static constexpr int SP  = ND1*ND2*ND3;        // 819200
static constexpr int CO  = 64;
static constexpr int OD1=80, OD2=80, OD3=32;
static constexpr int OSP = OD1*OD2*OD3;        // 204800
static constexpr int NSC = 64;

typedef __attribute__((ext_vector_type(8))) short  short8;
typedef __attribute__((ext_vector_type(4))) float  f32x4;

__device__ __forceinline__ float b2f(unsigned u){ return __uint_as_float(u<<16); }
__device__ __forceinline__ unsigned short f2b(float f){
    unsigned u = __float_as_uint(f);
    u += 0x7fffu + ((u>>16)&1u);
    return (unsigned short)(u>>16);
}

// ---------------- mask dtype detection ----------------
__global__ void k_detect(const unsigned char* __restrict__ mb, int* __restrict__ flag)
{
    __shared__ int lf;
    if (threadIdx.x == 0) lf = 0;
    __syncthreads();
    int f = 0;
    for (int i = blockIdx.x*256 + threadIdx.x; i < SP; i += gridDim.x*256) {
        unsigned char b = mb[i];
        if (b > 1) f |= 4;
        if (b != 0 && (i & 3)) f |= 1;
    }
    if (f) atomicOr(&lf, f);
    __syncthreads();
    if (threadIdx.x == 0 && lf) atomicOr(flag, lf);
}

__global__ void k_mask(const void* __restrict__ mraw, const int* __restrict__ flag,
                       float* __restrict__ m, float* __restrict__ nactN)
{
    int i = blockIdx.x*256 + threadIdx.x;
    int f = *flag;
    float v;
    if (f & 4)      v = (reinterpret_cast<const float*>(mraw)[i] != 0.f) ? 1.f : 0.f;
    else if (f & 1) v = (reinterpret_cast<const unsigned char*>(mraw)[i] != 0) ? 1.f : 0.f;
    else            v = (reinterpret_cast<const int*>(mraw)[i] != 0) ? 1.f : 0.f;
    m[i] = v;
    float s = v;
    #pragma unroll
    for (int off = 32; off > 0; off >>= 1) s += __shfl_xor(s, off);
    __shared__ float wsum[4];
    if ((threadIdx.x & 63) == 0) wsum[threadIdx.x >> 6] = s;
    __syncthreads();
    if (threadIdx.x == 0) atomicAdd(&nactN[blockIdx.x & (NSC-1)], wsum[0]+wsum[1]+wsum[2]+wsum[3]);
}

// ---------------- BN finalize (2 stages/launch) ----------------
__global__ void k_finalize2(const float* __restrict__ SN0, const float* __restrict__ g0,
                            const float* __restrict__ b0, float* __restrict__ o0,
                            const float* __restrict__ SN1, const float* __restrict__ g1,
                            const float* __restrict__ b1, float* __restrict__ o1,
                            const float* __restrict__ nactN)
{
    const float* SN = blockIdx.x ? SN1 : SN0;
    const float* g  = blockIdx.x ? g1  : g0;
    const float* b  = blockIdx.x ? b1  : b0;
    float*       o  = blockIdx.x ? o1  : o0;
    int c = threadIdx.x;
    float s1 = 0.f, s2 = 0.f;
    #pragma unroll 4
    for (int k = 0; k < NSC; k++){
        s1 += SN[k*128 + c];
        s2 += SN[k*128 + 64 + c];
    }
    float nn = nactN[c];
    #pragma unroll
    for (int off = 32; off > 0; off >>= 1) nn += __shfl_xor(nn, off);
    float mean = s1 / nn;
    float var  = s2 / nn - mean*mean;
    float inv  = rsqrtf(var + 1e-5f);
    float sc   = inv * g[c];
    o[c]      = sc;
    o[64 + c] = b[c] - mean*sc;
}

// ---------------- merged weight pre-pack (all 5 tensors, one launch) ----------------
__global__ void k_wprep_all(const float* __restrict__ WA1, const float* __restrict__ WA2,
                            const float* __restrict__ WB1, const float* __restrict__ WB2,
                            const float* __restrict__ WP,
                            unsigned short* __restrict__ tA1, unsigned short* __restrict__ tA2,
                            unsigned short* __restrict__ tB1, unsigned short* __restrict__ tB2,
                            unsigned short* __restrict__ tP)
{
    int i = blockIdx.x*256 + threadIdx.x;
    const float* W; unsigned short* Wt; int CIN, NT, base;
    if      (i < 18432)  { W=WA1; Wt=tA1; CIN=32; NT=9;  base=0; }
    else if (i < 55296)  { W=WA2; Wt=tA2; CIN=64; NT=9;  base=18432; }
    else if (i < 73728)  { W=WB1; Wt=tB1; CIN=32; NT=9;  base=55296; }
    else if (i < 110592) { W=WB2; Wt=tB2; CIN=64; NT=9;  base=73728; }
    else if (i < 221184) { W=WP;  Wt=tP;  CIN=64; NT=27; base=110592; }
    else return;
    int j = i - base;
    int ksub = j & 31;
    int t = j >> 5;
    int co = t & 63;
    int kc = t >> 6;
    int nch = CIN >> 5;
    int tap = kc / nch;
    int ci  = (kc - tap*nch)*32 + ksub;
    Wt[j] = f2b(W[((size_t)co*CIN + ci)*NT + tap]);
}

// ---------------- x f32 [ci][sp] -> masked bf16 [sp][32]  (+ out_mask in first 800 blocks) ----------------
__global__ void k_prep_x(const float* __restrict__ x, const float* __restrict__ m,
                         unsigned short* __restrict__ xt, float* __restrict__ om)
{
    __shared__ float t[64][33];
    int sp0 = blockIdx.x*64;
    int tid = threadIdx.x;
    int c = tid>>6, s = tid&63;
    float mm = m[sp0+s];
    #pragma unroll
    for (int r=0;r<8;r++){
        int ci = c + r*4;
        t[s][ci] = x[(size_t)ci*SP + sp0 + s]*mm;
    }
    __syncthreads();
    int sp = tid>>2, c0 = (tid&3)*8;
    unsigned short o[8];
    #pragma unroll
    for (int i=0;i<8;i++) o[i] = f2b(t[sp][c0+i]);
    uint4 pk;
    pk.x = o[0] | ((unsigned)o[1]<<16);
    pk.y = o[2] | ((unsigned)o[3]<<16);
    pk.z = o[4] | ((unsigned)o[5]<<16);
    pk.w = o[6] | ((unsigned)o[7]<<16);
    *reinterpret_cast<uint4*>(xt + (size_t)(sp0+sp)*32 + c0) = pk;

    // fold out_mask: first OSP/256 blocks each handle 256 output voxels
    if (blockIdx.x < OSP/256){
        int i = blockIdx.x*256 + tid;
        int o3 = i & 31; int tt = i >> 5; int o2 = tt % OD2; int o1 = tt / OD2;
        float ssum = 0.f;
        for (int kd = 0; kd < 3; kd++) { int d1 = 2*o1 - 1 + kd; if ((unsigned)d1 >= ND1) continue;
          for (int kh = 0; kh < 3; kh++) { int d2 = 2*o2 - 1 + kh; if ((unsigned)d2 >= ND2) continue;
            for (int kw = 0; kw < 3; kw++) { int d3 = o3 - 1 + kw; if ((unsigned)d3 >= ND3) continue;
              ssum += m[(d1*ND2 + d2)*ND3 + d3];
            } } }
        om[i] = (ssum > 0.f) ? 1.f : 0.f;
    }
}

// ---------------- res_B combine ----------------
__global__ void k_resB(const unsigned short* __restrict__ hA, const unsigned short* __restrict__ hB,
                       const float* __restrict__ sA, const float* __restrict__ sB,
                       const float* __restrict__ m,
                       unsigned short* __restrict__ rbt, float* __restrict__ resf)
{
    __shared__ float t[64][65];
    __shared__ float ss[256];
    int tid = threadIdx.x;
    if (tid < 128){ ss[tid] = sA[tid]; ss[128+tid] = sB[tid]; }
    __syncthreads();
    int sp0 = blockIdx.x*64;
    int sp = tid>>2, c0 = (tid&3)*16;
    float mm = m[sp0+sp];
    const size_t base = (size_t)(sp0+sp)*64 + c0;
    uint4 a0 = *reinterpret_cast<const uint4*>(hA + base);
    uint4 a1 = *reinterpret_cast<const uint4*>(hA + base + 8);
    uint4 b0 = *reinterpret_cast<const uint4*>(hB + base);
    uint4 b1 = *reinterpret_cast<const uint4*>(hB + base + 8);
    unsigned ua[16] = {a0.x&0xffffu,a0.x>>16,a0.y&0xffffu,a0.y>>16,a0.z&0xffffu,a0.z>>16,a0.w&0xffffu,a0.w>>16,
                       a1.x&0xffffu,a1.x>>16,a1.y&0xffffu,a1.y>>16,a1.z&0xffffu,a1.z>>16,a1.w&0xffffu,a1.w>>16};
    unsigned ub[16] = {b0.x&0xffffu,b0.x>>16,b0.y&0xffffu,b0.y>>16,b0.z&0xffffu,b0.z>>16,b0.w&0xffffu,b0.w>>16,
                       b1.x&0xffffu,b1.x>>16,b1.y&0xffffu,b1.y>>16,b1.z&0xffffu,b1.z>>16,b1.w&0xffffu,b1.w>>16};
    unsigned short o[16];
    #pragma unroll
    for (int q=0;q<16;q++){
        int ci = c0+q;
        float v = (b2f(ua[q])*ss[ci] + ss[64+ci] + b2f(ub[q])*ss[128+ci] + ss[192+ci])*mm;
        t[sp][ci] = v;
        o[q] = f2b(v);
    }
    uint4 p0, p1;
    p0.x = o[0]|((unsigned)o[1]<<16);  p0.y = o[2]|((unsigned)o[3]<<16);
    p0.z = o[4]|((unsigned)o[5]<<16);  p0.w = o[6]|((unsigned)o[7]<<16);
    p1.x = o[8]|((unsigned)o[9]<<16);  p1.y = o[10]|((unsigned)o[11]<<16);
    p1.z = o[12]|((unsigned)o[13]<<16); p1.w = o[14]|((unsigned)o[15]<<16);
    *reinterpret_cast<uint4*>(rbt + base)     = p0;
    *reinterpret_cast<uint4*>(rbt + base + 8) = p1;
    __syncthreads();
    int ci = tid>>2, s0 = (tid&3)*16;
    #pragma unroll
    for (int kq=0;kq<4;kq++){
        float4 ov;
        ov.x = t[s0+4*kq+0][ci]; ov.y = t[s0+4*kq+1][ci];
        ov.z = t[s0+4*kq+2][ci]; ov.w = t[s0+4*kq+3][ci];
        *reinterpret_cast<float4*>(resf + (size_t)ci*SP + sp0 + s0 + 4*kq) = ov;
    }
}

// ---------------- dual MFMA conv: two convs in one launch (runtime kind), weights in regs ----------------
// half A: blocks 0..3199, half B: blocks 3200..6399.
template<int CIN, bool HASAFF, int KA, int KB>
__launch_bounds__(256, (CIN==32) ? 3 : 2)
__global__ void mconv_dual(const unsigned short* __restrict__ inA, const unsigned short* __restrict__ WtA,
                           const float* __restrict__ scshA, unsigned short* __restrict__ outA,
                           float* __restrict__ statsA,
                           const unsigned short* __restrict__ inB, const unsigned short* __restrict__ WtB,
                           const float* __restrict__ scshB, unsigned short* __restrict__ outB2,
                           float* __restrict__ statsB,
                           const float* __restrict__ mstage, const float* __restrict__ mout)
{
    constexpr int NCH  = CIN/32;
    constexpr int NKC  = NCH*9;
    constexpr int NR   = 10;
    constexpr int ROWB = 34*CIN*2;
    constexpr int SWZ  = (CIN==64) ? 7 : 3;
    __shared__ __align__(16) char lds[NR*ROWB];
    __shared__ float sst[128];

    const int tid = threadIdx.x;
    const int w = tid>>6, l = tid&63, g = l>>4, lj = l&15;
    const int h = w&1, rg = w>>1;

    const int bid  = blockIdx.x;
    const int hb   = (bid >= 3200) ? 1 : 0;
    const int b2   = bid - hb*3200;
    const int gi   = (b2&7)*400 + (b2>>3);
    const int kind = hb ? KB : KA;
    const unsigned short* in  = hb ? inB   : inA;
    const unsigned short* Wt  = hb ? WtB   : WtA;
    const float*        scsh  = hb ? scshB : scshA;
    unsigned short*     outb  = hb ? outB2 : outA;
    float*             statsN = hb ? statsB : statsA;

    int z  = gi % 160;
    int r0 = (gi / 160)*8;

    if (tid < 128) sst[tid] = 0.f;

    const int sd3 = tid>>3;
    const int k0  = (tid&7)*(CIN/8);

    float sc[8], sh[8];
    if (HASAFF){
        #pragma unroll
        for (int j=0;j<8;j++){ sc[j]=scsh[k0+j]; sh[j]=scsh[64+k0+j]; }
    }

    for (int i = tid; i < NR*2*(CIN/8); i += 256){
        int per = CIN/8;
        int rr = i / (2*per);
        int rem = i - rr*2*per;
        int slot = (rem >= per) ? 33 : 0;
        int kc16 = (rem >= per) ? (rem - per) : rem;
        int dst = rr*ROWB + slot*CIN*2 + kc16*16;
        dst ^= ((slot&SWZ)<<4);
        *reinterpret_cast<uint4*>(lds + dst) = make_uint4(0,0,0,0);
    }

    if (CIN==64){
        uint4 v[NR]; float mmr[NR];
        #pragma unroll
        for (int rr=0; rr<NR; rr++){
            int rw = r0 - 1 + rr;
            v[rr] = make_uint4(0,0,0,0); mmr[rr] = 0.f;
            if ((unsigned)rw < 160u){
                int vox = (kind==0) ? ((rw*ND2 + z)*ND3 + sd3)
                                    : ((z*ND2 + rw)*ND3 + sd3);
                v[rr] = *reinterpret_cast<const uint4*>(in + (size_t)vox*CIN + k0);
                if (HASAFF) mmr[rr] = mstage[vox];
            }
        }
        #pragma unroll
        for (int rr=0; rr<NR; rr++){
            uint4 vv = v[rr];
            if (HASAFF){
                float mm = mmr[rr];
                unsigned us[8] = {vv.x&0xffffu,vv.x>>16,vv.y&0xffffu,vv.y>>16,
                                  vv.z&0xffffu,vv.z>>16,vv.w&0xffffu,vv.w>>16};
                unsigned short o[8];
                #pragma unroll
                for (int j=0;j<8;j++) o[j] = f2b((b2f(us[j])*sc[j]+sh[j])*mm);
                vv.x = o[0]|((unsigned)o[1]<<16); vv.y = o[2]|((unsigned)o[3]<<16);
                vv.z = o[4]|((unsigned)o[5]<<16); vv.w = o[6]|((unsigned)o[7]<<16);
            }
            int dst = (rr*ROWB + (((sd3+1)*CIN + k0)*2)) ^ (((sd3+1)&SWZ)<<4);
            *reinterpret_cast<uint4*>(lds + dst) = vv;
        }
    } else {
        uint2 v[NR];
        #pragma unroll
        for (int rr=0; rr<NR; rr++){
            int rw = r0 - 1 + rr;
            v[rr] = make_uint2(0,0);
            if ((unsigned)rw < 160u){
                int vox = (kind==0) ? ((rw*ND2 + z)*ND3 + sd3)
                                    : ((z*ND2 + rw)*ND3 + sd3);
                v[rr] = *reinterpret_cast<const uint2*>(in + (size_t)vox*CIN + k0);
            }
        }
        #pragma unroll
        for (int rr=0; rr<NR; rr++){
            int dst = (rr*ROWB + (((sd3+1)*CIN + k0)*2)) ^ (((sd3+1)&SWZ)<<4);
            *reinterpret_cast<uint2*>(lds + dst) = v[rr];
        }
    }

    short8 pa[NKC][2];
    {
        const unsigned short* wb = Wt + (size_t)(h*32)*32 + lj*32 + g*8;
        #pragma unroll
        for (int kc=0; kc<NKC; kc++){
            pa[kc][0] = *reinterpret_cast<const short8*>(wb + (size_t)kc*2048);
            pa[kc][1] = *reinterpret_cast<const short8*>(wb + (size_t)kc*2048 + 512);
        }
    }

    int tb[8], ovox[8];
    float mm[8];
    #pragma unroll
    for (int t=0;t<8;t++){
        int rowb = rg*4 + (t>>1);
        int o3   = (t&1)*16 + lj;
        tb[t] = rowb*ROWB + ((o3*CIN + g*8)*2);
        int o2r = r0 + rowb;
        ovox[t] = (kind==0) ? ((o2r*ND2 + z)*ND3 + o3)
                            : ((z*ND2 + o2r)*ND3 + o3);
        mm[t] = mout[ovox[t]];
    }
    int swz[3];
    #pragma unroll
    for (int kw=0;kw<3;kw++) swz[kw] = ((lj+kw)&SWZ)<<4;

    __syncthreads();

    f32x4 acc[2][8];
    #pragma unroll
    for (int c=0;c<2;c++)
        #pragma unroll
        for (int t=0;t<8;t++)
            #pragma unroll
            for (int q=0;q<4;q++) acc[c][t][q] = 0.f;

    #pragma unroll
    for (int ch=0; ch<NCH; ch++){
        #pragma unroll
        for (int tap=0; tap<9; tap++){
            const int kd = tap/3, kw = tap - kd*3;
            const int kc = tap*NCH + ch;
            const int tapoff = kd*ROWB + (kw*CIN + ch*32)*2;
            #pragma unroll
            for (int t=0;t<8;t++){
                int off = (tb[t] + tapoff) ^ swz[kw];
                short8 bv = *reinterpret_cast<const short8*>(lds + off);
                acc[0][t] = __builtin_amdgcn_mfma_f32_16x16x32_bf16(pa[kc][0], bv, acc[0][t], 0,0,0);
                acc[1][t] = __builtin_amdgcn_mfma_f32_16x16x32_bf16(pa[kc][1], bv, acc[1][t], 0,0,0);
            }
        }
    }

    #pragma unroll
    for (int c=0;c<2;c++){
        const int ct = h*2 + c;
        float s1[4] = {0.f,0.f,0.f,0.f};
        float s2[4] = {0.f,0.f,0.f,0.f};
        #pragma unroll
        for (int t=0;t<8;t++){
            float v[4];
            #pragma unroll
            for (int r=0;r<4;r++){
                float xv = acc[c][t][r]*mm[t];
                xv = (xv >= 0.f) ? xv : 0.01f*xv;
                v[r] = xv; s1[r] += xv; s2[r] += xv*xv;
            }
            unsigned lo = f2b(v[0]) | ((unsigned)f2b(v[1])<<16);
            unsigned hi = f2b(v[2]) | ((unsigned)f2b(v[3])<<16);
            *reinterpret_cast<uint2*>(outb + (size_t)ovox[t]*64 + ct*16 + g*4) = make_uint2(lo,hi);
        }
        #pragma unroll
        for (int r=0;r<4;r++){
            float a = s1[r], b = s2[r];
            a += __shfl_xor(a,1); b += __shfl_xor(b,1);
            a += __shfl_xor(a,2); b += __shfl_xor(b,2);
            a += __shfl_xor(a,4); b += __shfl_xor(b,4);
            a += __shfl_xor(a,8); b += __shfl_xor(b,8);
            if (lj == 0){
                atomicAdd(&sst[ct*16 + g*4 + r], a);
                atomicAdd(&sst[64 + ct*16 + g*4 + r], b);
            }
        }
    }
    __syncthreads();
    if (tid < 128){
        float* sg = statsN + (size_t)(blockIdx.x & (NSC-1))*128;
        atomicAdd(&sg[tid], sst[tid]);
    }
}

// ---------------- pool conv: ch-phase staging, pad-80 rows, coalesced output ----------------
__launch_bounds__(256, 2)
__global__ void mpool5(const unsigned short* __restrict__ in,   // bf16 [vox][64]
                       const unsigned short* __restrict__ Wt,   // bf16 [kc][64co][32k]
                       const float* __restrict__ mout,          // out_mask
                       float* __restrict__ outf)                // f32 [co][OSP]
{
    constexpr int SLOTB = 80;
    constexpr int ROWB  = 34*SLOTB;    // 2720
    extern __shared__ __align__(16) char lds[];   // 27*ROWB = 73440

    const int tid = threadIdx.x;
    const int w = tid>>6, l = tid&63, g = l>>4, lj = l&15;
    const int h = w&1, rg = w>>1;

    int gi = (blockIdx.x & 7)*(gridDim.x>>3) + (blockIdx.x>>3);
    int z  = gi % OD1;
    int r0 = (gi / OD1)*4;

    const int sd3 = tid>>3;
    const int kq  = tid&7;

    for (int i = tid; i < 27*2*4; i += 256){
        int row = i >> 3, rem = i & 7;
        int slot = (rem >= 4) ? 33 : 0;
        int c16 = rem & 3;
        *reinterpret_cast<uint4*>(lds + row*ROWB + slot*SLOTB + c16*16) = make_uint4(0,0,0,0);
    }

    int ovx[4];
    float om[4];
    #pragma unroll
    for (int t=0;t<4;t++){
        int row = rg*2 + (t>>1);
        int o3  = (t&1)*16 + lj;
        ovx[t] = (z*OD2 + (r0 + row))*OD3 + o3;
        om[t]  = mout[ovx[t]];
    }

    f32x4 acc[2][4];
    #pragma unroll
    for (int c=0;c<2;c++)
        #pragma unroll
        for (int t=0;t<4;t++)
            #pragma unroll
            for (int q=0;q<4;q++) acc[c][t][q] = 0.f;

    const unsigned short* wbase = Wt + (size_t)(h*32)*32 + lj*32 + g*8;

    #pragma unroll 1
    for (int ph=0; ph<2; ph++){
        uint2 v[27];
        #pragma unroll
        for (int i=0;i<27;i++){
            const int kd = i/9, rr = i - (i/9)*9;
            int d1 = 2*z - 1 + kd;
            int d2 = 2*r0 - 1 + rr;
            v[i] = make_uint2(0,0);
            if ((unsigned)d1 < (unsigned)ND1 && (unsigned)d2 < (unsigned)ND2){
                int vox = (d1*ND2 + d2)*ND3 + sd3;
                v[i] = *reinterpret_cast<const uint2*>(in + (size_t)vox*64 + ph*32 + kq*4);
            }
        }
        __syncthreads();
        #pragma unroll
        for (int i=0;i<27;i++){
            *reinterpret_cast<uint2*>(lds + i*ROWB + (sd3+1)*SLOTB + kq*8) = v[i];
        }
        __syncthreads();

        #pragma unroll
        for (int kd=0; kd<3; kd++){
            short8 pa[9][2];
            #pragma unroll
            for (int tap=0; tap<9; tap++){
                const int kc = (kd*9 + tap)*2 + ph;
                pa[tap][0] = *reinterpret_cast<const short8*>(wbase + (size_t)kc*2048);
                pa[tap][1] = *reinterpret_cast<const short8*>(wbase + (size_t)kc*2048 + 512);
            }
            #pragma unroll
            for (int tap=0; tap<9; tap++){
                const int kh = tap/3, kw = tap - (tap/3)*3;
                #pragma unroll
                for (int t=0;t<4;t++){
                    const int rr = 2*(rg*2 + (t>>1)) + kh;
                    const int slot = (t&1)*16 + lj + kw;
                    const char* bp = lds + (kd*9 + rr)*ROWB + slot*SLOTB + g*16;
                    short8 bv = *reinterpret_cast<const short8*>(bp);
                    acc[0][t] = __builtin_amdgcn_mfma_f32_16x16x32_bf16(pa[tap][0], bv, acc[0][t], 0,0,0);
                    acc[1][t] = __builtin_amdgcn_mfma_f32_16x16x32_bf16(pa[tap][1], bv, acc[1][t], 0,0,0);
                }
            }
        }
    }

    // ---- coalesced epilogue via LDS bounce: [co][4 rows x 32 o3] f32 = 32 KB ----
    __syncthreads();
    float* olds = (float*)lds;
    #pragma unroll
    for (int c=0;c<2;c++){
        const int ct = h*2 + c;
        #pragma unroll
        for (int t=0;t<4;t++){
            int row = rg*2 + (t>>1);
            int o3  = (t&1)*16 + lj;
            #pragma unroll
            for (int r=0;r<4;r++){
                int co = ct*16 + g*4 + r;
                olds[co*128 + row*32 + o3] = acc[c][t][r]*om[t];
            }
        }
    }
    __syncthreads();
    const size_t obase = (size_t)(z*OD2 + r0)*OD3;
    #pragma unroll
    for (int i=0;i<8;i++){
        int idx = i*256 + tid;     // 0..2047
        int co  = idx >> 5;        // 32 x 16B per co
        int q   = idx & 31;
        uint4 v = *reinterpret_cast<uint4*>(reinterpret_cast<char*>(olds) + co*512 + q*16);
        *reinterpret_cast<uint4*>(outf + (size_t)co*OSP + obase + q*4) = v;
    }
}

// ---------------- launch ----------------
extern "C" void kernel_launch(void* const* d_in, const int* in_sizes, int n_in,
                              void* d_out, int out_size, void* d_ws, size_t ws_size,
                              hipStream_t stream)
{
    const float* x      = (const float*)d_in[0];
    const void*  mraw   = d_in[1];
    const float* W_A1   = (const float*)d_in[2];
    const float* W_A2   = (const float*)d_in[3];
    const float* W_B1   = (const float*)d_in[4];
    const float* W_B2   = (const float*)d_in[5];
    const float* W_pool = (const float*)d_in[6];
    const float* g_A1 = (const float*)d_in[7],  *b_A1 = (const float*)d_in[8];
    const float* g_A2 = (const float*)d_in[9],  *b_A2 = (const float*)d_in[10];
    const float* g_B1 = (const float*)d_in[11], *b_B1 = (const float*)d_in[12];
    const float* g_B2 = (const float*)d_in[13], *b_B2 = (const float*)d_in[14];

    char* p = (char*)d_ws;
    float* m     = (float*)p; p += (size_t)SP*4;
    float* omask = (float*)p; p += (size_t)OSP*4;
    float* statsN= (float*)p; p += 4*NSC*128*4;
    float* scsh  = (float*)p; p += 4*128*4;
    float* nactN = (float*)p; p += NSC*4;
    int*   flag  = (int*)p;   p += 4;
    p += 252;
    unsigned short* WtA1 = (unsigned short*)p; p += 288*64*2;
    unsigned short* WtA2 = (unsigned short*)p; p += 576*64*2;
    unsigned short* WtB1 = (unsigned short*)p; p += 288*64*2;
    unsigned short* WtB2 = (unsigned short*)p; p += 576*64*2;
    unsigned short* WtP  = (unsigned short*)p; p += 1728*64*2;
    unsigned short* X = (unsigned short*)p; p += (size_t)SP*32*2;
    unsigned short* P = (unsigned short*)p; p += (size_t)SP*64*2;
    unsigned short* Q = (unsigned short*)p; p += (size_t)SP*64*2;
    unsigned short* R = (unsigned short*)p; p += (size_t)SP*64*2;
    unsigned short* S = (unsigned short*)p; p += (size_t)SP*64*2;

    float* down = (float*)d_out;                 // [64][OSP]
    float* resf = down + (size_t)CO*OSP;         // [64][SP]

    const int shmP = 27*34*80;                   // 73440
    hipFuncSetAttribute((const void*)&mpool5, hipFuncAttributeMaxDynamicSharedMemorySize, shmP);

    hipMemsetAsync(statsN, 0, (4*NSC*128 + 4*128 + NSC)*4 + 4, stream);
    k_detect<<<256, 256, 0, stream>>>((const unsigned char*)mraw, flag);
    k_mask<<<SP/256, 256, 0, stream>>>(mraw, flag, m, nactN);
    k_wprep_all<<<864, 256, 0, stream>>>(W_A1, W_A2, W_B1, W_B2, W_pool,
                                         WtA1, WtA2, WtB1, WtB2, WtP);
    k_prep_x<<<SP/64, 256, 0, stream>>>(x, m, X, omask);

    float* SA1 = statsN + 0*NSC*128;
    float* SA2 = statsN + 1*NSC*128;
    float* SB1 = statsN + 2*NSC*128;
    float* SB2 = statsN + 3*NSC*128;

    // stage 1: A1 (KIND0, X->P) + B1 (KIND1, X->Q) in one launch
    mconv_dual<32,false,0,1><<<6400, 256, 0, stream>>>(
        X, WtA1, nullptr, P, SA1,
        X, WtB1, nullptr, Q, SB1, nullptr, m);
    k_finalize2<<<2, 64, 0, stream>>>(SA1, g_A1, b_A1, scsh + 0,
                                      SB1, g_B1, b_B1, scsh + 256, nactN);
    // stage 2: A2 (KIND1, P->R) + B2 (KIND0, Q->S) in one launch (disjoint in/out)
    mconv_dual<64,true,1,0><<<6400, 256, 0, stream>>>(
        P, WtA2, scsh + 0,   R, SA2,
        Q, WtB2, scsh + 256, S, SB2, m, m);
    k_finalize2<<<2, 64, 0, stream>>>(SA2, g_A2, b_A2, scsh + 128,
                                      SB2, g_B2, b_B2, scsh + 384, nactN);
    // res_B combine -> Q (bf16 for pool) + resf (f32 output)
    k_resB<<<SP/64, 256, 0, stream>>>(R, S, scsh + 128, scsh + 384, m, Q, resf);
    // pool
    mpool5<<<1600, 256, shmP, stream>>>(Q, WtP, omask, down);
}

// Round 15
// 582.322 us; speedup vs baseline: 1.2011x; 1.0968x over previous
//
#include <hip/hip_runtime.h>

static constexpr int ND1=160, ND2=160, ND3=32;
static constexpr int SP  = ND1*ND2*ND3;        // 819200
static constexpr int CO  = 64;
static constexpr int OD1=80, OD2=80, OD3=32;
static constexpr int OSP = OD1*OD2*OD3;        // 204800
static constexpr int NSC = 64;

typedef __attribute__((ext_vector_type(8))) short  short8;
typedef __attribute__((ext_vector_type(4))) float  f32x4;

__device__ __forceinline__ float b2f(unsigned u){ return __uint_as_float(u<<16); }
__device__ __forceinline__ unsigned short f2b(float f){
    unsigned u = __float_as_uint(f);
    u += 0x7fffu + ((u>>16)&1u);
    return (unsigned short)(u>>16);
}

// ---------------- mask dtype detection ----------------
__global__ void k_detect(const unsigned char* __restrict__ mb, int* __restrict__ flag)
{
    __shared__ int lf;
    if (threadIdx.x == 0) lf = 0;
    __syncthreads();
    int f = 0;
    for (int i = blockIdx.x*256 + threadIdx.x; i < SP; i += gridDim.x*256) {
        unsigned char b = mb[i];
        if (b > 1) f |= 4;
        if (b != 0 && (i & 3)) f |= 1;
    }
    if (f) atomicOr(&lf, f);
    __syncthreads();
    if (threadIdx.x == 0 && lf) atomicOr(flag, lf);
}

__global__ void k_mask(const void* __restrict__ mraw, const int* __restrict__ flag,
                       float* __restrict__ m, float* __restrict__ nactN)
{
    int i = blockIdx.x*256 + threadIdx.x;
    int f = *flag;
    float v;
    if (f & 4)      v = (reinterpret_cast<const float*>(mraw)[i] != 0.f) ? 1.f : 0.f;
    else if (f & 1) v = (reinterpret_cast<const unsigned char*>(mraw)[i] != 0) ? 1.f : 0.f;
    else            v = (reinterpret_cast<const int*>(mraw)[i] != 0) ? 1.f : 0.f;
    m[i] = v;
    float s = v;
    #pragma unroll
    for (int off = 32; off > 0; off >>= 1) s += __shfl_xor(s, off);
    __shared__ float wsum[4];
    if ((threadIdx.x & 63) == 0) wsum[threadIdx.x >> 6] = s;
    __syncthreads();
    if (threadIdx.x == 0) atomicAdd(&nactN[blockIdx.x & (NSC-1)], wsum[0]+wsum[1]+wsum[2]+wsum[3]);
}

// ---------------- BN finalize (2 stages/launch) ----------------
__global__ void k_finalize2(const float* __restrict__ SN0, const float* __restrict__ g0,
                            const float* __restrict__ b0, float* __restrict__ o0,
                            const float* __restrict__ SN1, const float* __restrict__ g1,
                            const float* __restrict__ b1, float* __restrict__ o1,
                            const float* __restrict__ nactN)
{
    const float* SN = blockIdx.x ? SN1 : SN0;
    const float* g  = blockIdx.x ? g1  : g0;
    const float* b  = blockIdx.x ? b1  : b0;
    float*       o  = blockIdx.x ? o1  : o0;
    int c = threadIdx.x;
    float s1 = 0.f, s2 = 0.f;
    #pragma unroll 4
    for (int k = 0; k < NSC; k++){
        s1 += SN[k*128 + c];
        s2 += SN[k*128 + 64 + c];
    }
    float nn = nactN[c];
    #pragma unroll
    for (int off = 32; off > 0; off >>= 1) nn += __shfl_xor(nn, off);
    float mean = s1 / nn;
    float var  = s2 / nn - mean*mean;
    float inv  = rsqrtf(var + 1e-5f);
    float sc   = inv * g[c];
    o[c]      = sc;
    o[64 + c] = b[c] - mean*sc;
}

// ---------------- merged weight pre-pack ----------------
__global__ void k_wprep_all(const float* __restrict__ WA1, const float* __restrict__ WA2,
                            const float* __restrict__ WB1, const float* __restrict__ WB2,
                            const float* __restrict__ WP,
                            unsigned short* __restrict__ tA1, unsigned short* __restrict__ tA2,
                            unsigned short* __restrict__ tB1, unsigned short* __restrict__ tB2,
                            unsigned short* __restrict__ tP)
{
    int i = blockIdx.x*256 + threadIdx.x;
    const float* W; unsigned short* Wt; int CIN, NT, base;
    if      (i < 18432)  { W=WA1; Wt=tA1; CIN=32; NT=9;  base=0; }
    else if (i < 55296)  { W=WA2; Wt=tA2; CIN=64; NT=9;  base=18432; }
    else if (i < 73728)  { W=WB1; Wt=tB1; CIN=32; NT=9;  base=55296; }
    else if (i < 110592) { W=WB2; Wt=tB2; CIN=64; NT=9;  base=73728; }
    else if (i < 221184) { W=WP;  Wt=tP;  CIN=64; NT=27; base=110592; }
    else return;
    int j = i - base;
    int ksub = j & 31;
    int t = j >> 5;
    int co = t & 63;
    int kc = t >> 6;
    int nch = CIN >> 5;
    int tap = kc / nch;
    int ci  = (kc - tap*nch)*32 + ksub;
    Wt[j] = f2b(W[((size_t)co*CIN + ci)*NT + tap]);
}

// ---------------- x prep (+ out_mask fold) ----------------
__global__ void k_prep_x(const float* __restrict__ x, const float* __restrict__ m,
                         unsigned short* __restrict__ xt, float* __restrict__ om)
{
    __shared__ float t[64][33];
    int sp0 = blockIdx.x*64;
    int tid = threadIdx.x;
    int c = tid>>6, s = tid&63;
    float mm = m[sp0+s];
    #pragma unroll
    for (int r=0;r<8;r++){
        int ci = c + r*4;
        t[s][ci] = x[(size_t)ci*SP + sp0 + s]*mm;
    }
    __syncthreads();
    int sp = tid>>2, c0 = (tid&3)*8;
    unsigned short o[8];
    #pragma unroll
    for (int i=0;i<8;i++) o[i] = f2b(t[sp][c0+i]);
    uint4 pk;
    pk.x = o[0] | ((unsigned)o[1]<<16);
    pk.y = o[2] | ((unsigned)o[3]<<16);
    pk.z = o[4] | ((unsigned)o[5]<<16);
    pk.w = o[6] | ((unsigned)o[7]<<16);
    *reinterpret_cast<uint4*>(xt + (size_t)(sp0+sp)*32 + c0) = pk;

    if (blockIdx.x < OSP/256){
        int i = blockIdx.x*256 + tid;
        int o3 = i & 31; int tt = i >> 5; int o2 = tt % OD2; int o1 = tt / OD2;
        float ssum = 0.f;
        for (int kd = 0; kd < 3; kd++) { int d1 = 2*o1 - 1 + kd; if ((unsigned)d1 >= ND1) continue;
          for (int kh = 0; kh < 3; kh++) { int d2 = 2*o2 - 1 + kh; if ((unsigned)d2 >= ND2) continue;
            for (int kw = 0; kw < 3; kw++) { int d3 = o3 - 1 + kw; if ((unsigned)d3 >= ND3) continue;
              ssum += m[(d1*ND2 + d2)*ND3 + d3];
            } } }
        om[i] = (ssum > 0.f) ? 1.f : 0.f;
    }
}

// ---------------- res_B combine ----------------
__global__ void k_resB(const unsigned short* __restrict__ hA, const unsigned short* __restrict__ hB,
                       const float* __restrict__ sA, const float* __restrict__ sB,
                       const float* __restrict__ m,
                       unsigned short* __restrict__ rbt, float* __restrict__ resf)
{
    __shared__ float t[64][65];
    __shared__ float ss[256];
    int tid = threadIdx.x;
    if (tid < 128){ ss[tid] = sA[tid]; ss[128+tid] = sB[tid]; }
    __syncthreads();
    int sp0 = blockIdx.x*64;
    int sp = tid>>2, c0 = (tid&3)*16;
    float mm = m[sp0+sp];
    const size_t base = (size_t)(sp0+sp)*64 + c0;
    uint4 a0 = *reinterpret_cast<const uint4*>(hA + base);
    uint4 a1 = *reinterpret_cast<const uint4*>(hA + base + 8);
    uint4 b0 = *reinterpret_cast<const uint4*>(hB + base);
    uint4 b1 = *reinterpret_cast<const uint4*>(hB + base + 8);
    unsigned ua[16] = {a0.x&0xffffu,a0.x>>16,a0.y&0xffffu,a0.y>>16,a0.z&0xffffu,a0.z>>16,a0.w&0xffffu,a0.w>>16,
                       a1.x&0xffffu,a1.x>>16,a1.y&0xffffu,a1.y>>16,a1.z&0xffffu,a1.z>>16,a1.w&0xffffu,a1.w>>16};
    unsigned ub[16] = {b0.x&0xffffu,b0.x>>16,b0.y&0xffffu,b0.y>>16,b0.z&0xffffu,b0.z>>16,b0.w&0xffffu,b0.w>>16,
                       b1.x&0xffffu,b1.x>>16,b1.y&0xffffu,b1.y>>16,b1.z&0xffffu,b1.z>>16,b1.w&0xffffu,b1.w>>16};
    unsigned short o[16];
    #pragma unroll
    for (int q=0;q<16;q++){
        int ci = c0+q;
        float v = (b2f(ua[q])*ss[ci] + ss[64+ci] + b2f(ub[q])*ss[128+ci] + ss[192+ci])*mm;
        t[sp][ci] = v;
        o[q] = f2b(v);
    }
    uint4 p0, p1;
    p0.x = o[0]|((unsigned)o[1]<<16);  p0.y = o[2]|((unsigned)o[3]<<16);
    p0.z = o[4]|((unsigned)o[5]<<16);  p0.w = o[6]|((unsigned)o[7]<<16);
    p1.x = o[8]|((unsigned)o[9]<<16);  p1.y = o[10]|((unsigned)o[11]<<16);
    p1.z = o[12]|((unsigned)o[13]<<16); p1.w = o[14]|((unsigned)o[15]<<16);
    *reinterpret_cast<uint4*>(rbt + base)     = p0;
    *reinterpret_cast<uint4*>(rbt + base + 8) = p1;
    __syncthreads();
    int ci = tid>>2, s0 = (tid&3)*16;
    #pragma unroll
    for (int kq=0;kq<4;kq++){
        float4 ov;
        ov.x = t[s0+4*kq+0][ci]; ov.y = t[s0+4*kq+1][ci];
        ov.z = t[s0+4*kq+2][ci]; ov.w = t[s0+4*kq+3][ci];
        *reinterpret_cast<float4*>(resf + (size_t)ci*SP + sp0 + s0 + 4*kq) = ov;
    }
}

// ---------------- dual MFMA conv: per-ch weight regs, coalesced LDS-bounce output ----------------
// half A: blocks 0..3199, half B: blocks 3200..6399.
template<int CIN, bool HASAFF, int KA, int KB>
__launch_bounds__(256, 3)
__global__ void mconv_dual(const unsigned short* __restrict__ inA, const unsigned short* __restrict__ WtA,
                           const float* __restrict__ scshA, unsigned short* __restrict__ outA,
                           float* __restrict__ statsA,
                           const unsigned short* __restrict__ inB, const unsigned short* __restrict__ WtB,
                           const float* __restrict__ scshB, unsigned short* __restrict__ outB2,
                           float* __restrict__ statsB,
                           const float* __restrict__ mstage, const float* __restrict__ mout)
{
    constexpr int NCH  = CIN/32;
    constexpr int NR   = 10;
    constexpr int ROWB = 34*CIN*2;
    constexpr int SWZ  = (CIN==64) ? 7 : 3;
    constexpr int OBST = 144;                       // bounce stride per voxel (16B-aligned)
    constexpr int LDSZ = (NR*ROWB > 256*OBST) ? NR*ROWB : 256*OBST;
    __shared__ __align__(16) char lds[LDSZ];
    __shared__ float sst[128];

    const int tid = threadIdx.x;
    const int w = tid>>6, l = tid&63, g = l>>4, lj = l&15;
    const int h = w&1, rg = w>>1;

    const int bid  = blockIdx.x;
    const int hb   = (bid >= 3200) ? 1 : 0;
    const int b2   = bid - hb*3200;
    const int gi   = (b2&7)*400 + (b2>>3);
    const int kind = hb ? KB : KA;
    const unsigned short* in  = hb ? inB   : inA;
    const unsigned short* Wt  = hb ? WtB   : WtA;
    const float*        scsh  = hb ? scshB : scshA;
    unsigned short*     outb  = hb ? outB2 : outA;
    float*             statsN = hb ? statsB : statsA;

    int z  = gi % 160;
    int r0 = (gi / 160)*8;

    if (tid < 128) sst[tid] = 0.f;

    const int sd3 = tid>>3;
    const int k0  = (tid&7)*(CIN/8);

    float sc[8], sh[8];
    if (HASAFF){
        #pragma unroll
        for (int j=0;j<8;j++){ sc[j]=scsh[k0+j]; sh[j]=scsh[64+k0+j]; }
    }

    // border zeros (slots 0 and 33)
    for (int i = tid; i < NR*2*(CIN/8); i += 256){
        int per = CIN/8;
        int rr = i / (2*per);
        int rem = i - rr*2*per;
        int slot = (rem >= per) ? 33 : 0;
        int kc16 = (rem >= per) ? (rem - per) : rem;
        int dst = rr*ROWB + slot*CIN*2 + kc16*16;
        dst ^= ((slot&SWZ)<<4);
        *reinterpret_cast<uint4*>(lds + dst) = make_uint4(0,0,0,0);
    }

    // stage full-CIN rows, batched, slot-XOR swizzled
    if (CIN==64){
        uint4 v[NR]; float mmr[NR];
        #pragma unroll
        for (int rr=0; rr<NR; rr++){
            int rw = r0 - 1 + rr;
            v[rr] = make_uint4(0,0,0,0); mmr[rr] = 0.f;
            if ((unsigned)rw < 160u){
                int vox = (kind==0) ? ((rw*ND2 + z)*ND3 + sd3)
                                    : ((z*ND2 + rw)*ND3 + sd3);
                v[rr] = *reinterpret_cast<const uint4*>(in + (size_t)vox*CIN + k0);
                if (HASAFF) mmr[rr] = mstage[vox];
            }
        }
        #pragma unroll
        for (int rr=0; rr<NR; rr++){
            uint4 vv = v[rr];
            if (HASAFF){
                float mm = mmr[rr];
                unsigned us[8] = {vv.x&0xffffu,vv.x>>16,vv.y&0xffffu,vv.y>>16,
                                  vv.z&0xffffu,vv.z>>16,vv.w&0xffffu,vv.w>>16};
                unsigned short o[8];
                #pragma unroll
                for (int j=0;j<8;j++) o[j] = f2b((b2f(us[j])*sc[j]+sh[j])*mm);
                vv.x = o[0]|((unsigned)o[1]<<16); vv.y = o[2]|((unsigned)o[3]<<16);
                vv.z = o[4]|((unsigned)o[5]<<16); vv.w = o[6]|((unsigned)o[7]<<16);
            }
            int dst = (rr*ROWB + (((sd3+1)*CIN + k0)*2)) ^ (((sd3+1)&SWZ)<<4);
            *reinterpret_cast<uint4*>(lds + dst) = vv;
        }
    } else {
        uint2 v[NR];
        #pragma unroll
        for (int rr=0; rr<NR; rr++){
            int rw = r0 - 1 + rr;
            v[rr] = make_uint2(0,0);
            if ((unsigned)rw < 160u){
                int vox = (kind==0) ? ((rw*ND2 + z)*ND3 + sd3)
                                    : ((z*ND2 + rw)*ND3 + sd3);
                v[rr] = *reinterpret_cast<const uint2*>(in + (size_t)vox*CIN + k0);
            }
        }
        #pragma unroll
        for (int rr=0; rr<NR; rr++){
            int dst = (rr*ROWB + (((sd3+1)*CIN + k0)*2)) ^ (((sd3+1)&SWZ)<<4);
            *reinterpret_cast<uint2*>(lds + dst) = v[rr];
        }
    }

    int tb[8];
    #pragma unroll
    for (int t=0;t<8;t++){
        int rowb = rg*4 + (t>>1);
        int o3   = (t&1)*16 + lj;
        tb[t] = rowb*ROWB + ((o3*CIN + g*8)*2);
    }
    int swz[3];
    #pragma unroll
    for (int kw=0;kw<3;kw++) swz[kw] = ((lj+kw)&SWZ)<<4;

    __syncthreads();

    f32x4 acc[2][8];
    #pragma unroll
    for (int c=0;c<2;c++)
        #pragma unroll
        for (int t=0;t<8;t++)
            #pragma unroll
            for (int q=0;q<4;q++) acc[c][t][q] = 0.f;

    const unsigned short* wb = Wt + (size_t)(h*32)*32 + lj*32 + g*8;

    #pragma unroll 1
    for (int ch=0; ch<NCH; ch++){
        short8 pa[9][2];
        #pragma unroll
        for (int tap=0; tap<9; tap++){
            const int kc = tap*NCH + ch;
            pa[tap][0] = *reinterpret_cast<const short8*>(wb + (size_t)kc*2048);
            pa[tap][1] = *reinterpret_cast<const short8*>(wb + (size_t)kc*2048 + 512);
        }
        #pragma unroll
        for (int tap=0; tap<9; tap++){
            const int kd = tap/3, kw = tap - kd*3;
            const int tapoff = kd*ROWB + (kw*CIN + ch*32)*2;
            #pragma unroll
            for (int t=0;t<8;t++){
                int off = (tb[t] + tapoff) ^ swz[kw];
                short8 bv = *reinterpret_cast<const short8*>(lds + off);
                acc[0][t] = __builtin_amdgcn_mfma_f32_16x16x32_bf16(pa[tap][0], bv, acc[0][t], 0,0,0);
                acc[1][t] = __builtin_amdgcn_mfma_f32_16x16x32_bf16(pa[tap][1], bv, acc[1][t], 0,0,0);
            }
        }
    }

    __syncthreads();    // compute done everywhere; lds reusable as bounce buffer

    // epilogue: mask, lrelu, stats; bounce to LDS [256 vox][144B]
    float mmv[8];
    #pragma unroll
    for (int t=0;t<8;t++){
        int rowb = rg*4 + (t>>1);
        int o3   = (t&1)*16 + lj;
        int o2r  = r0 + rowb;
        int ovox = (kind==0) ? ((o2r*ND2 + z)*ND3 + o3)
                             : ((z*ND2 + o2r)*ND3 + o3);
        mmv[t] = mout[ovox];
    }
    #pragma unroll
    for (int c=0;c<2;c++){
        const int ct = h*2 + c;
        float s1[4] = {0.f,0.f,0.f,0.f};
        float s2[4] = {0.f,0.f,0.f,0.f};
        #pragma unroll
        for (int t=0;t<8;t++){
            int rowb = rg*4 + (t>>1);
            int o3   = (t&1)*16 + lj;
            int vloc = rowb*32 + o3;
            float v[4];
            #pragma unroll
            for (int r=0;r<4;r++){
                float xv = acc[c][t][r]*mmv[t];
                xv = (xv >= 0.f) ? xv : 0.01f*xv;
                v[r] = xv; s1[r] += xv; s2[r] += xv*xv;
            }
            unsigned lo = f2b(v[0]) | ((unsigned)f2b(v[1])<<16);
            unsigned hi = f2b(v[2]) | ((unsigned)f2b(v[3])<<16);
            *reinterpret_cast<uint2*>(lds + vloc*OBST + (ct*16 + g*4)*2) = make_uint2(lo,hi);
        }
        #pragma unroll
        for (int r=0;r<4;r++){
            float a = s1[r], b = s2[r];
            a += __shfl_xor(a,1); b += __shfl_xor(b,1);
            a += __shfl_xor(a,2); b += __shfl_xor(b,2);
            a += __shfl_xor(a,4); b += __shfl_xor(b,4);
            a += __shfl_xor(a,8); b += __shfl_xor(b,8);
            if (lj == 0){
                atomicAdd(&sst[ct*16 + g*4 + r], a);
                atomicAdd(&sst[64 + ct*16 + g*4 + r], b);
            }
        }
    }
    __syncthreads();
    // coalesced copy-out: 256 vox x 128B
    #pragma unroll
    for (int i=0;i<8;i++){
        int idx = i*256 + tid;
        int vloc = idx >> 3;
        int q    = idx & 7;
        int row  = vloc >> 5;
        int o3g  = vloc & 31;
        int gvox = (kind==0) ? (((r0+row)*ND2 + z)*ND3 + o3g)
                             : ((z*ND2 + (r0+row))*ND3 + o3g);
        uint4 v = *reinterpret_cast<uint4*>(lds + vloc*OBST + q*16);
        *reinterpret_cast<uint4*>(outb + (size_t)gvox*64 + q*8) = v;
    }
    if (tid < 128){
        float* sg = statsN + (size_t)(blockIdx.x & (NSC-1))*128;
        atomicAdd(&sg[tid], sst[tid]);
    }
}

// ---------------- pool conv (round-14 known-good) ----------------
__launch_bounds__(256, 2)
__global__ void mpool5(const unsigned short* __restrict__ in,
                       const unsigned short* __restrict__ Wt,
                       const float* __restrict__ mout,
                       float* __restrict__ outf)
{
    constexpr int SLOTB = 80;
    constexpr int ROWB  = 34*SLOTB;
    extern __shared__ __align__(16) char lds[];

    const int tid = threadIdx.x;
    const int w = tid>>6, l = tid&63, g = l>>4, lj = l&15;
    const int h = w&1, rg = w>>1;

    int gi = (blockIdx.x & 7)*(gridDim.x>>3) + (blockIdx.x>>3);
    int z  = gi % OD1;
    int r0 = (gi / OD1)*4;

    const int sd3 = tid>>3;
    const int kq  = tid&7;

    for (int i = tid; i < 27*2*4; i += 256){
        int row = i >> 3, rem = i & 7;
        int slot = (rem >= 4) ? 33 : 0;
        int c16 = rem & 3;
        *reinterpret_cast<uint4*>(lds + row*ROWB + slot*SLOTB + c16*16) = make_uint4(0,0,0,0);
    }

    int ovx[4];
    float om[4];
    #pragma unroll
    for (int t=0;t<4;t++){
        int row = rg*2 + (t>>1);
        int o3  = (t&1)*16 + lj;
        ovx[t] = (z*OD2 + (r0 + row))*OD3 + o3;
        om[t]  = mout[ovx[t]];
    }

    f32x4 acc[2][4];
    #pragma unroll
    for (int c=0;c<2;c++)
        #pragma unroll
        for (int t=0;t<4;t++)
            #pragma unroll
            for (int q=0;q<4;q++) acc[c][t][q] = 0.f;

    const unsigned short* wbase = Wt + (size_t)(h*32)*32 + lj*32 + g*8;

    #pragma unroll 1
    for (int ph=0; ph<2; ph++){
        uint2 v[27];
        #pragma unroll
        for (int i=0;i<27;i++){
            const int kd = i/9, rr = i - (i/9)*9;
            int d1 = 2*z - 1 + kd;
            int d2 = 2*r0 - 1 + rr;
            v[i] = make_uint2(0,0);
            if ((unsigned)d1 < (unsigned)ND1 && (unsigned)d2 < (unsigned)ND2){
                int vox = (d1*ND2 + d2)*ND3 + sd3;
                v[i] = *reinterpret_cast<const uint2*>(in + (size_t)vox*64 + ph*32 + kq*4);
            }
        }
        __syncthreads();
        #pragma unroll
        for (int i=0;i<27;i++){
            *reinterpret_cast<uint2*>(lds + i*ROWB + (sd3+1)*SLOTB + kq*8) = v[i];
        }
        __syncthreads();

        #pragma unroll
        for (int kd=0; kd<3; kd++){
            short8 pa[9][2];
            #pragma unroll
            for (int tap=0; tap<9; tap++){
                const int kc = (kd*9 + tap)*2 + ph;
                pa[tap][0] = *reinterpret_cast<const short8*>(wbase + (size_t)kc*2048);
                pa[tap][1] = *reinterpret_cast<const short8*>(wbase + (size_t)kc*2048 + 512);
            }
            #pragma unroll
            for (int tap=0; tap<9; tap++){
                const int kh = tap/3, kw = tap - (tap/3)*3;
                #pragma unroll
                for (int t=0;t<4;t++){
                    const int rr = 2*(rg*2 + (t>>1)) + kh;
                    const int slot = (t&1)*16 + lj + kw;
                    const char* bp = lds + (kd*9 + rr)*ROWB + slot*SLOTB + g*16;
                    short8 bv = *reinterpret_cast<const short8*>(bp);
                    acc[0][t] = __builtin_amdgcn_mfma_f32_16x16x32_bf16(pa[tap][0], bv, acc[0][t], 0,0,0);
                    acc[1][t] = __builtin_amdgcn_mfma_f32_16x16x32_bf16(pa[tap][1], bv, acc[1][t], 0,0,0);
                }
            }
        }
    }

    __syncthreads();
    float* olds = (float*)lds;
    #pragma unroll
    for (int c=0;c<2;c++){
        const int ct = h*2 + c;
        #pragma unroll
        for (int t=0;t<4;t++){
            int row = rg*2 + (t>>1);
            int o3  = (t&1)*16 + lj;
            #pragma unroll
            for (int r=0;r<4;r++){
                int co = ct*16 + g*4 + r;
                olds[co*128 + row*32 + o3] = acc[c][t][r]*om[t];
            }
        }
    }
    __syncthreads();
    const size_t obase = (size_t)(z*OD2 + r0)*OD3;
    #pragma unroll
    for (int i=0;i<8;i++){
        int idx = i*256 + tid;
        int co  = idx >> 5;
        int q   = idx & 31;
        uint4 v = *reinterpret_cast<uint4*>(reinterpret_cast<char*>(olds) + co*512 + q*16);
        *reinterpret_cast<uint4*>(outf + (size_t)co*OSP + obase + q*4) = v;
    }
}

// ---------------- launch ----------------
extern "C" void kernel_launch(void* const* d_in, const int* in_sizes, int n_in,
                              void* d_out, int out_size, void* d_ws, size_t ws_size,
                              hipStream_t stream)
{
    const float* x      = (const float*)d_in[0];
    const void*  mraw   = d_in[1];
    const float* W_A1   = (const float*)d_in[2];
    const float* W_A2   = (const float*)d_in[3];
    const float* W_B1   = (const float*)d_in[4];
    const float* W_B2   = (const float*)d_in[5];
    const float* W_pool = (const float*)d_in[6];
    const float* g_A1 = (const float*)d_in[7],  *b_A1 = (const float*)d_in[8];
    const float* g_A2 = (const float*)d_in[9],  *b_A2 = (const float*)d_in[10];
    const float* g_B1 = (const float*)d_in[11], *b_B1 = (const float*)d_in[12];
    const float* g_B2 = (const float*)d_in[13], *b_B2 = (const float*)d_in[14];

    char* p = (char*)d_ws;
    float* m     = (float*)p; p += (size_t)SP*4;
    float* omask = (float*)p; p += (size_t)OSP*4;
    float* statsN= (float*)p; p += 4*NSC*128*4;
    float* scsh  = (float*)p; p += 4*128*4;
    float* nactN = (float*)p; p += NSC*4;
    int*   flag  = (int*)p;   p += 4;
    p += 252;
    unsigned short* WtA1 = (unsigned short*)p; p += 288*64*2;
    unsigned short* WtA2 = (unsigned short*)p; p += 576*64*2;
    unsigned short* WtB1 = (unsigned short*)p; p += 288*64*2;
    unsigned short* WtB2 = (unsigned short*)p; p += 576*64*2;
    unsigned short* WtP  = (unsigned short*)p; p += 1728*64*2;
    unsigned short* X = (unsigned short*)p; p += (size_t)SP*32*2;
    unsigned short* P = (unsigned short*)p; p += (size_t)SP*64*2;
    unsigned short* Q = (unsigned short*)p; p += (size_t)SP*64*2;
    unsigned short* R = (unsigned short*)p; p += (size_t)SP*64*2;
    unsigned short* S = (unsigned short*)p; p += (size_t)SP*64*2;

    float* down = (float*)d_out;                 // [64][OSP]
    float* resf = down + (size_t)CO*OSP;         // [64][SP]

    const int shmP = 27*34*80;                   // 73440
    hipFuncSetAttribute((const void*)&mpool5, hipFuncAttributeMaxDynamicSharedMemorySize, shmP);

    hipMemsetAsync(statsN, 0, (4*NSC*128 + 4*128 + NSC)*4 + 4, stream);
    k_detect<<<256, 256, 0, stream>>>((const unsigned char*)mraw, flag);
    k_mask<<<SP/256, 256, 0, stream>>>(mraw, flag, m, nactN);
    k_wprep_all<<<864, 256, 0, stream>>>(W_A1, W_A2, W_B1, W_B2, W_pool,
                                         WtA1, WtA2, WtB1, WtB2, WtP);
    k_prep_x<<<SP/64, 256, 0, stream>>>(x, m, X, omask);

    float* SA1 = statsN + 0*NSC*128;
    float* SA2 = statsN + 1*NSC*128;
    float* SB1 = statsN + 2*NSC*128;
    float* SB2 = statsN + 3*NSC*128;

    // stage 1: A1 (KIND0, X->P) + B1 (KIND1, X->Q)
    mconv_dual<32,false,0,1><<<6400, 256, 0, stream>>>(
        X, WtA1, nullptr, P, SA1,
        X, WtB1, nullptr, Q, SB1, nullptr, m);
    k_finalize2<<<2, 64, 0, stream>>>(SA1, g_A1, b_A1, scsh + 0,
                                      SB1, g_B1, b_B1, scsh + 256, nactN);
    // stage 2: A2 (KIND1, P->R) + B2 (KIND0, Q->S)
    mconv_dual<64,true,1,0><<<6400, 256, 0, stream>>>(
        P, WtA2, scsh + 0,   R, SA2,
        Q, WtB2, scsh + 256, S, SB2, m, m);
    k_finalize2<<<2, 64, 0, stream>>>(SA2, g_A2, b_A2, scsh + 128,
                                      SB2, g_B2, b_B2, scsh + 384, nactN);
    // res_B combine -> Q (bf16 for pool) + resf (f32 output)
    k_resB<<<SP/64, 256, 0, stream>>>(R, S, scsh + 128, scsh + 384, m, Q, resf);
    // pool
    mpool5<<<1600, 256, shmP, stream>>>(Q, WtP, omask, down);
}

// Round 16
// 572.835 us; speedup vs baseline: 1.2210x; 1.0166x over previous
//
#include <hip/hip_runtime.h>

static constexpr int ND1=160, ND2=160, ND3=32;
static constexpr int SP  = ND1*ND2*ND3;        // 819200
static constexpr int CO  = 64;
static constexpr int OD1=80, OD2=80, OD3=32;
static constexpr int OSP = OD1*OD2*OD3;        // 204800
static constexpr int NSC = 64;

typedef __attribute__((ext_vector_type(8))) short  short8;
typedef __attribute__((ext_vector_type(4))) float  f32x4;

__device__ __forceinline__ float b2f(unsigned u){ return __uint_as_float(u<<16); }
__device__ __forceinline__ unsigned short f2b(float f){
    unsigned u = __float_as_uint(f);
    u += 0x7fffu + ((u>>16)&1u);
    return (unsigned short)(u>>16);
}
// packed f32x2 -> bf16x2 (RNE), 1 VALU inst
__device__ __forceinline__ unsigned cvtpk(float lo, float hi){
    unsigned r;
    asm("v_cvt_pk_bf16_f32 %0, %1, %2" : "=v"(r) : "v"(lo), "v"(hi));
    return r;
}
__device__ __forceinline__ float lrelu(float x){ return fmaxf(x, 0.01f*x); }

// ---------------- mask dtype detection ----------------
__global__ void k_detect(const unsigned char* __restrict__ mb, int* __restrict__ flag)
{
    __shared__ int lf;
    if (threadIdx.x == 0) lf = 0;
    __syncthreads();
    int f = 0;
    for (int i = blockIdx.x*256 + threadIdx.x; i < SP; i += gridDim.x*256) {
        unsigned char b = mb[i];
        if (b > 1) f |= 4;
        if (b != 0 && (i & 3)) f |= 1;
    }
    if (f) atomicOr(&lf, f);
    __syncthreads();
    if (threadIdx.x == 0 && lf) atomicOr(flag, lf);
}

__global__ void k_mask(const void* __restrict__ mraw, const int* __restrict__ flag,
                       float* __restrict__ m, float* __restrict__ nactN)
{
    int i = blockIdx.x*256 + threadIdx.x;
    int f = *flag;
    float v;
    if (f & 4)      v = (reinterpret_cast<const float*>(mraw)[i] != 0.f) ? 1.f : 0.f;
    else if (f & 1) v = (reinterpret_cast<const unsigned char*>(mraw)[i] != 0) ? 1.f : 0.f;
    else            v = (reinterpret_cast<const int*>(mraw)[i] != 0) ? 1.f : 0.f;
    m[i] = v;
    float s = v;
    #pragma unroll
    for (int off = 32; off > 0; off >>= 1) s += __shfl_xor(s, off);
    __shared__ float wsum[4];
    if ((threadIdx.x & 63) == 0) wsum[threadIdx.x >> 6] = s;
    __syncthreads();
    if (threadIdx.x == 0) atomicAdd(&nactN[blockIdx.x & (NSC-1)], wsum[0]+wsum[1]+wsum[2]+wsum[3]);
}

// ---------------- BN finalize (2 stages/launch) ----------------
__global__ void k_finalize2(const float* __restrict__ SN0, const float* __restrict__ g0,
                            const float* __restrict__ b0, float* __restrict__ o0,
                            const float* __restrict__ SN1, const float* __restrict__ g1,
                            const float* __restrict__ b1, float* __restrict__ o1,
                            const float* __restrict__ nactN)
{
    const float* SN = blockIdx.x ? SN1 : SN0;
    const float* g  = blockIdx.x ? g1  : g0;
    const float* b  = blockIdx.x ? b1  : b0;
    float*       o  = blockIdx.x ? o1  : o0;
    int c = threadIdx.x;
    float s1 = 0.f, s2 = 0.f;
    #pragma unroll 4
    for (int k = 0; k < NSC; k++){
        s1 += SN[k*128 + c];
        s2 += SN[k*128 + 64 + c];
    }
    float nn = nactN[c];
    #pragma unroll
    for (int off = 32; off > 0; off >>= 1) nn += __shfl_xor(nn, off);
    float mean = s1 / nn;
    float var  = s2 / nn - mean*mean;
    float inv  = rsqrtf(var + 1e-5f);
    float sc   = inv * g[c];
    o[c]      = sc;
    o[64 + c] = b[c] - mean*sc;
}

// ---------------- merged weight pre-pack ----------------
__global__ void k_wprep_all(const float* __restrict__ WA1, const float* __restrict__ WA2,
                            const float* __restrict__ WB1, const float* __restrict__ WB2,
                            const float* __restrict__ WP,
                            unsigned short* __restrict__ tA1, unsigned short* __restrict__ tA2,
                            unsigned short* __restrict__ tB1, unsigned short* __restrict__ tB2,
                            unsigned short* __restrict__ tP)
{
    int i = blockIdx.x*256 + threadIdx.x;
    const float* W; unsigned short* Wt; int CIN, NT, base;
    if      (i < 18432)  { W=WA1; Wt=tA1; CIN=32; NT=9;  base=0; }
    else if (i < 55296)  { W=WA2; Wt=tA2; CIN=64; NT=9;  base=18432; }
    else if (i < 73728)  { W=WB1; Wt=tB1; CIN=32; NT=9;  base=55296; }
    else if (i < 110592) { W=WB2; Wt=tB2; CIN=64; NT=9;  base=73728; }
    else if (i < 221184) { W=WP;  Wt=tP;  CIN=64; NT=27; base=110592; }
    else return;
    int j = i - base;
    int ksub = j & 31;
    int t = j >> 5;
    int co = t & 63;
    int kc = t >> 6;
    int nch = CIN >> 5;
    int tap = kc / nch;
    int ci  = (kc - tap*nch)*32 + ksub;
    Wt[j] = f2b(W[((size_t)co*CIN + ci)*NT + tap]);
}

// ---------------- x prep (+ out_mask fold) ----------------
__global__ void k_prep_x(const float* __restrict__ x, const float* __restrict__ m,
                         unsigned short* __restrict__ xt, float* __restrict__ om)
{
    __shared__ float t[64][33];
    int sp0 = blockIdx.x*64;
    int tid = threadIdx.x;
    int c = tid>>6, s = tid&63;
    float mm = m[sp0+s];
    #pragma unroll
    for (int r=0;r<8;r++){
        int ci = c + r*4;
        t[s][ci] = x[(size_t)ci*SP + sp0 + s]*mm;
    }
    __syncthreads();
    int sp = tid>>2, c0 = (tid&3)*8;
    uint4 pk;
    pk.x = cvtpk(t[sp][c0+0], t[sp][c0+1]);
    pk.y = cvtpk(t[sp][c0+2], t[sp][c0+3]);
    pk.z = cvtpk(t[sp][c0+4], t[sp][c0+5]);
    pk.w = cvtpk(t[sp][c0+6], t[sp][c0+7]);
    *reinterpret_cast<uint4*>(xt + (size_t)(sp0+sp)*32 + c0) = pk;

    if (blockIdx.x < OSP/256){
        int i = blockIdx.x*256 + tid;
        int o3 = i & 31; int tt = i >> 5; int o2 = tt % OD2; int o1 = tt / OD2;
        float ssum = 0.f;
        for (int kd = 0; kd < 3; kd++) { int d1 = 2*o1 - 1 + kd; if ((unsigned)d1 >= ND1) continue;
          for (int kh = 0; kh < 3; kh++) { int d2 = 2*o2 - 1 + kh; if ((unsigned)d2 >= ND2) continue;
            for (int kw = 0; kw < 3; kw++) { int d3 = o3 - 1 + kw; if ((unsigned)d3 >= ND3) continue;
              ssum += m[(d1*ND2 + d2)*ND3 + d3];
            } } }
        om[i] = (ssum > 0.f) ? 1.f : 0.f;
    }
}

// ---------------- res_B combine ----------------
__global__ void k_resB(const unsigned short* __restrict__ hA, const unsigned short* __restrict__ hB,
                       const float* __restrict__ sA, const float* __restrict__ sB,
                       const float* __restrict__ m,
                       unsigned short* __restrict__ rbt, float* __restrict__ resf)
{
    __shared__ float t[64][65];
    __shared__ float ss[256];
    int tid = threadIdx.x;
    if (tid < 128){ ss[tid] = sA[tid]; ss[128+tid] = sB[tid]; }
    __syncthreads();
    int sp0 = blockIdx.x*64;
    int sp = tid>>2, c0 = (tid&3)*16;
    float mm = m[sp0+sp];
    const size_t base = (size_t)(sp0+sp)*64 + c0;
    uint4 a0 = *reinterpret_cast<const uint4*>(hA + base);
    uint4 a1 = *reinterpret_cast<const uint4*>(hA + base + 8);
    uint4 b0 = *reinterpret_cast<const uint4*>(hB + base);
    uint4 b1 = *reinterpret_cast<const uint4*>(hB + base + 8);
    unsigned ua[16] = {a0.x&0xffffu,a0.x>>16,a0.y&0xffffu,a0.y>>16,a0.z&0xffffu,a0.z>>16,a0.w&0xffffu,a0.w>>16,
                       a1.x&0xffffu,a1.x>>16,a1.y&0xffffu,a1.y>>16,a1.z&0xffffu,a1.z>>16,a1.w&0xffffu,a1.w>>16};
    unsigned ub[16] = {b0.x&0xffffu,b0.x>>16,b0.y&0xffffu,b0.y>>16,b0.z&0xffffu,b0.z>>16,b0.w&0xffffu,b0.w>>16,
                       b1.x&0xffffu,b1.x>>16,b1.y&0xffffu,b1.y>>16,b1.z&0xffffu,b1.z>>16,b1.w&0xffffu,b1.w>>16};
    float vv[16];
    #pragma unroll
    for (int q=0;q<16;q++){
        int ci = c0+q;
        float v = (b2f(ua[q])*ss[ci] + ss[64+ci] + b2f(ub[q])*ss[128+ci] + ss[192+ci])*mm;
        t[sp][ci] = v;
        vv[q] = v;
    }
    uint4 p0, p1;
    p0.x = cvtpk(vv[0],vv[1]);   p0.y = cvtpk(vv[2],vv[3]);
    p0.z = cvtpk(vv[4],vv[5]);   p0.w = cvtpk(vv[6],vv[7]);
    p1.x = cvtpk(vv[8],vv[9]);   p1.y = cvtpk(vv[10],vv[11]);
    p1.z = cvtpk(vv[12],vv[13]); p1.w = cvtpk(vv[14],vv[15]);
    *reinterpret_cast<uint4*>(rbt + base)     = p0;
    *reinterpret_cast<uint4*>(rbt + base + 8) = p1;
    __syncthreads();
    int ci = tid>>2, s0 = (tid&3)*16;
    #pragma unroll
    for (int kq=0;kq<4;kq++){
        float4 ov;
        ov.x = t[s0+4*kq+0][ci]; ov.y = t[s0+4*kq+1][ci];
        ov.z = t[s0+4*kq+2][ci]; ov.w = t[s0+4*kq+3][ci];
        *reinterpret_cast<float4*>(resf + (size_t)ci*SP + sp0 + s0 + 4*kq) = ov;
    }
}

// ---------------- dual MFMA conv: per-ch weight regs, cvt_pk epilogue, coalesced bounce ----------------
template<int CIN, bool HASAFF, int KA, int KB>
__launch_bounds__(256, 3)
__global__ void mconv_dual(const unsigned short* __restrict__ inA, const unsigned short* __restrict__ WtA,
                           const float* __restrict__ scshA, unsigned short* __restrict__ outA,
                           float* __restrict__ statsA,
                           const unsigned short* __restrict__ inB, const unsigned short* __restrict__ WtB,
                           const float* __restrict__ scshB, unsigned short* __restrict__ outB2,
                           float* __restrict__ statsB,
                           const float* __restrict__ mstage, const float* __restrict__ mout)
{
    constexpr int NCH  = CIN/32;
    constexpr int NR   = 10;
    constexpr int ROWB = 34*CIN*2;
    constexpr int SWZ  = (CIN==64) ? 7 : 3;
    constexpr int OBST = 160;                       // bounce stride: bank-friendly (2-way)
    constexpr int LDSZ = (NR*ROWB > 256*OBST) ? NR*ROWB : 256*OBST;
    __shared__ __align__(16) char lds[LDSZ];
    __shared__ float sst[128];

    const int tid = threadIdx.x;
    const int w = tid>>6, l = tid&63, g = l>>4, lj = l&15;
    const int h = w&1, rg = w>>1;

    const int bid  = blockIdx.x;
    const int hb   = (bid >= 3200) ? 1 : 0;
    const int b2   = bid - hb*3200;
    const int gi   = (b2&7)*400 + (b2>>3);
    const int kind = hb ? KB : KA;
    const unsigned short* in  = hb ? inB   : inA;
    const unsigned short* Wt  = hb ? WtB   : WtA;
    const float*        scsh  = hb ? scshB : scshA;
    unsigned short*     outb  = hb ? outB2 : outA;
    float*             statsN = hb ? statsB : statsA;

    int z  = gi % 160;
    int r0 = (gi / 160)*8;

    if (tid < 128) sst[tid] = 0.f;

    const int sd3 = tid>>3;
    const int k0  = (tid&7)*(CIN/8);

    float sc[8], sh[8];
    if (HASAFF){
        #pragma unroll
        for (int j=0;j<8;j++){ sc[j]=scsh[k0+j]; sh[j]=scsh[64+k0+j]; }
    }

    // border zeros (slots 0 and 33)
    for (int i = tid; i < NR*2*(CIN/8); i += 256){
        int per = CIN/8;
        int rr = i / (2*per);
        int rem = i - rr*2*per;
        int slot = (rem >= per) ? 33 : 0;
        int kc16 = (rem >= per) ? (rem - per) : rem;
        int dst = rr*ROWB + slot*CIN*2 + kc16*16;
        dst ^= ((slot&SWZ)<<4);
        *reinterpret_cast<uint4*>(lds + dst) = make_uint4(0,0,0,0);
    }

    // stage full-CIN rows, batched, slot-XOR swizzled
    if (CIN==64){
        uint4 v[NR]; float mmr[NR];
        #pragma unroll
        for (int rr=0; rr<NR; rr++){
            int rw = r0 - 1 + rr;
            v[rr] = make_uint4(0,0,0,0); mmr[rr] = 0.f;
            if ((unsigned)rw < 160u){
                int vox = (kind==0) ? ((rw*ND2 + z)*ND3 + sd3)
                                    : ((z*ND2 + rw)*ND3 + sd3);
                v[rr] = *reinterpret_cast<const uint4*>(in + (size_t)vox*CIN + k0);
                if (HASAFF) mmr[rr] = mstage[vox];
            }
        }
        #pragma unroll
        for (int rr=0; rr<NR; rr++){
            uint4 vv = v[rr];
            if (HASAFF){
                float mm = mmr[rr];
                float q0 = (b2f(vv.x&0xffffu)*sc[0]+sh[0])*mm;
                float q1 = (b2f(vv.x>>16    )*sc[1]+sh[1])*mm;
                float q2 = (b2f(vv.y&0xffffu)*sc[2]+sh[2])*mm;
                float q3 = (b2f(vv.y>>16    )*sc[3]+sh[3])*mm;
                float q4 = (b2f(vv.z&0xffffu)*sc[4]+sh[4])*mm;
                float q5 = (b2f(vv.z>>16    )*sc[5]+sh[5])*mm;
                float q6 = (b2f(vv.w&0xffffu)*sc[6]+sh[6])*mm;
                float q7 = (b2f(vv.w>>16    )*sc[7]+sh[7])*mm;
                vv.x = cvtpk(q0,q1); vv.y = cvtpk(q2,q3);
                vv.z = cvtpk(q4,q5); vv.w = cvtpk(q6,q7);
            }
            int dst = (rr*ROWB + (((sd3+1)*CIN + k0)*2)) ^ (((sd3+1)&SWZ)<<4);
            *reinterpret_cast<uint4*>(lds + dst) = vv;
        }
    } else {
        uint2 v[NR];
        #pragma unroll
        for (int rr=0; rr<NR; rr++){
            int rw = r0 - 1 + rr;
            v[rr] = make_uint2(0,0);
            if ((unsigned)rw < 160u){
                int vox = (kind==0) ? ((rw*ND2 + z)*ND3 + sd3)
                                    : ((z*ND2 + rw)*ND3 + sd3);
                v[rr] = *reinterpret_cast<const uint2*>(in + (size_t)vox*CIN + k0);
            }
        }
        #pragma unroll
        for (int rr=0; rr<NR; rr++){
            int dst = (rr*ROWB + (((sd3+1)*CIN + k0)*2)) ^ (((sd3+1)&SWZ)<<4);
            *reinterpret_cast<uint2*>(lds + dst) = v[rr];
        }
    }

    int tb[8];
    #pragma unroll
    for (int t=0;t<8;t++){
        int rowb = rg*4 + (t>>1);
        int o3   = (t&1)*16 + lj;
        tb[t] = rowb*ROWB + ((o3*CIN + g*8)*2);
    }
    int swz[3];
    #pragma unroll
    for (int kw=0;kw<3;kw++) swz[kw] = ((lj+kw)&SWZ)<<4;

    __syncthreads();

    f32x4 acc[2][8];
    #pragma unroll
    for (int c=0;c<2;c++)
        #pragma unroll
        for (int t=0;t<8;t++)
            #pragma unroll
            for (int q=0;q<4;q++) acc[c][t][q] = 0.f;

    const unsigned short* wb = Wt + (size_t)(h*32)*32 + lj*32 + g*8;

    #pragma unroll 1
    for (int ch=0; ch<NCH; ch++){
        short8 pa[9][2];
        #pragma unroll
        for (int tap=0; tap<9; tap++){
            const int kc = tap*NCH + ch;
            pa[tap][0] = *reinterpret_cast<const short8*>(wb + (size_t)kc*2048);
            pa[tap][1] = *reinterpret_cast<const short8*>(wb + (size_t)kc*2048 + 512);
        }
        #pragma unroll
        for (int tap=0; tap<9; tap++){
            const int kd = tap/3, kw = tap - kd*3;
            const int tapoff = kd*ROWB + (kw*CIN + ch*32)*2;
            #pragma unroll
            for (int t=0;t<8;t++){
                int off = (tb[t] + tapoff) ^ swz[kw];
                short8 bv = *reinterpret_cast<const short8*>(lds + off);
                acc[0][t] = __builtin_amdgcn_mfma_f32_16x16x32_bf16(pa[tap][0], bv, acc[0][t], 0,0,0);
                acc[1][t] = __builtin_amdgcn_mfma_f32_16x16x32_bf16(pa[tap][1], bv, acc[1][t], 0,0,0);
            }
        }
    }

    __syncthreads();    // compute done; lds reusable as bounce buffer

    float mmv[8];
    #pragma unroll
    for (int t=0;t<8;t++){
        int rowb = rg*4 + (t>>1);
        int o3   = (t&1)*16 + lj;
        int o2r  = r0 + rowb;
        int ovox = (kind==0) ? ((o2r*ND2 + z)*ND3 + o3)
                             : ((z*ND2 + o2r)*ND3 + o3);
        mmv[t] = mout[ovox];
    }
    #pragma unroll
    for (int c=0;c<2;c++){
        const int ct = h*2 + c;
        float s1[4] = {0.f,0.f,0.f,0.f};
        float s2[4] = {0.f,0.f,0.f,0.f};
        #pragma unroll
        for (int t=0;t<8;t++){
            int rowb = rg*4 + (t>>1);
            int o3   = (t&1)*16 + lj;
            int vloc = rowb*32 + o3;
            float v[4];
            #pragma unroll
            for (int r=0;r<4;r++){
                float xv = lrelu(acc[c][t][r]*mmv[t]);
                v[r] = xv; s1[r] += xv; s2[r] += xv*xv;
            }
            *reinterpret_cast<uint2*>(lds + vloc*OBST + (ct*16 + g*4)*2) =
                make_uint2(cvtpk(v[0],v[1]), cvtpk(v[2],v[3]));
        }
        #pragma unroll
        for (int r=0;r<4;r++){
            float a = s1[r], b = s2[r];
            a += __shfl_xor(a,1); b += __shfl_xor(b,1);
            a += __shfl_xor(a,2); b += __shfl_xor(b,2);
            a += __shfl_xor(a,4); b += __shfl_xor(b,4);
            a += __shfl_xor(a,8); b += __shfl_xor(b,8);
            if (lj == 0){
                atomicAdd(&sst[ct*16 + g*4 + r], a);
                atomicAdd(&sst[64 + ct*16 + g*4 + r], b);
            }
        }
    }
    __syncthreads();
    #pragma unroll
    for (int i=0;i<8;i++){
        int idx = i*256 + tid;
        int vloc = idx >> 3;
        int q    = idx & 7;
        int row  = vloc >> 5;
        int o3g  = vloc & 31;
        int gvox = (kind==0) ? (((r0+row)*ND2 + z)*ND3 + o3g)
                             : ((z*ND2 + (r0+row))*ND3 + o3g);
        uint4 v = *reinterpret_cast<uint4*>(lds + vloc*OBST + q*16);
        *reinterpret_cast<uint4*>(outb + (size_t)gvox*64 + q*8) = v;
    }
    if (tid < 128){
        float* sg = statsN + (size_t)(blockIdx.x & (NSC-1))*128;
        atomicAdd(&sg[tid], sst[tid]);
    }
}

// ---------------- pool conv (round-14/15 known-good) ----------------
__launch_bounds__(256, 2)
__global__ void mpool5(const unsigned short* __restrict__ in,
                       const unsigned short* __restrict__ Wt,
                       const float* __restrict__ mout,
                       float* __restrict__ outf)
{
    constexpr int SLOTB = 80;
    constexpr int ROWB  = 34*SLOTB;
    extern __shared__ __align__(16) char lds[];

    const int tid = threadIdx.x;
    const int w = tid>>6, l = tid&63, g = l>>4, lj = l&15;
    const int h = w&1, rg = w>>1;

    int gi = (blockIdx.x & 7)*(gridDim.x>>3) + (blockIdx.x>>3);
    int z  = gi % OD1;
    int r0 = (gi / OD1)*4;

    const int sd3 = tid>>3;
    const int kq  = tid&7;

    for (int i = tid; i < 27*2*4; i += 256){
        int row = i >> 3, rem = i & 7;
        int slot = (rem >= 4) ? 33 : 0;
        int c16 = rem & 3;
        *reinterpret_cast<uint4*>(lds + row*ROWB + slot*SLOTB + c16*16) = make_uint4(0,0,0,0);
    }

    int ovx[4];
    float om[4];
    #pragma unroll
    for (int t=0;t<4;t++){
        int row = rg*2 + (t>>1);
        int o3  = (t&1)*16 + lj;
        ovx[t] = (z*OD2 + (r0 + row))*OD3 + o3;
        om[t]  = mout[ovx[t]];
    }

    f32x4 acc[2][4];
    #pragma unroll
    for (int c=0;c<2;c++)
        #pragma unroll
        for (int t=0;t<4;t++)
            #pragma unroll
            for (int q=0;q<4;q++) acc[c][t][q] = 0.f;

    const unsigned short* wbase = Wt + (size_t)(h*32)*32 + lj*32 + g*8;

    #pragma unroll 1
    for (int ph=0; ph<2; ph++){
        uint2 v[27];
        #pragma unroll
        for (int i=0;i<27;i++){
            const int kd = i/9, rr = i - (i/9)*9;
            int d1 = 2*z - 1 + kd;
            int d2 = 2*r0 - 1 + rr;
            v[i] = make_uint2(0,0);
            if ((unsigned)d1 < (unsigned)ND1 && (unsigned)d2 < (unsigned)ND2){
                int vox = (d1*ND2 + d2)*ND3 + sd3;
                v[i] = *reinterpret_cast<const uint2*>(in + (size_t)vox*64 + ph*32 + kq*4);
            }
        }
        __syncthreads();
        #pragma unroll
        for (int i=0;i<27;i++){
            *reinterpret_cast<uint2*>(lds + i*ROWB + (sd3+1)*SLOTB + kq*8) = v[i];
        }
        __syncthreads();

        #pragma unroll
        for (int kd=0; kd<3; kd++){
            short8 pa[9][2];
            #pragma unroll
            for (int tap=0; tap<9; tap++){
                const int kc = (kd*9 + tap)*2 + ph;
                pa[tap][0] = *reinterpret_cast<const short8*>(wbase + (size_t)kc*2048);
                pa[tap][1] = *reinterpret_cast<const short8*>(wbase + (size_t)kc*2048 + 512);
            }
            #pragma unroll
            for (int tap=0; tap<9; tap++){
                const int kh = tap/3, kw = tap - (tap/3)*3;
                #pragma unroll
                for (int t=0;t<4;t++){
                    const int rr = 2*(rg*2 + (t>>1)) + kh;
                    const int slot = (t&1)*16 + lj + kw;
                    const char* bp = lds + (kd*9 + rr)*ROWB + slot*SLOTB + g*16;
                    short8 bv = *reinterpret_cast<const short8*>(bp);
                    acc[0][t] = __builtin_amdgcn_mfma_f32_16x16x32_bf16(pa[tap][0], bv, acc[0][t], 0,0,0);
                    acc[1][t] = __builtin_amdgcn_mfma_f32_16x16x32_bf16(pa[tap][1], bv, acc[1][t], 0,0,0);
                }
            }
        }
    }

    __syncthreads();
    float* olds = (float*)lds;
    #pragma unroll
    for (int c=0;c<2;c++){
        const int ct = h*2 + c;
        #pragma unroll
        for (int t=0;t<4;t++){
            int row = rg*2 + (t>>1);
            int o3  = (t&1)*16 + lj;
            #pragma unroll
            for (int r=0;r<4;r++){
                int co = ct*16 + g*4 + r;
                olds[co*128 + row*32 + o3] = acc[c][t][r]*om[t];
            }
        }
    }
    __syncthreads();
    const size_t obase = (size_t)(z*OD2 + r0)*OD3;
    #pragma unroll
    for (int i=0;i<8;i++){
        int idx = i*256 + tid;
        int co  = idx >> 5;
        int q   = idx & 31;
        uint4 v = *reinterpret_cast<uint4*>(reinterpret_cast<char*>(olds) + co*512 + q*16);
        *reinterpret_cast<uint4*>(outf + (size_t)co*OSP + obase + q*4) = v;
    }
}

// ---------------- launch ----------------
extern "C" void kernel_launch(void* const* d_in, const int* in_sizes, int n_in,
                              void* d_out, int out_size, void* d_ws, size_t ws_size,
                              hipStream_t stream)
{
    const float* x      = (const float*)d_in[0];
    const void*  mraw   = d_in[1];
    const float* W_A1   = (const float*)d_in[2];
    const float* W_A2   = (const float*)d_in[3];
    const float* W_B1   = (const float*)d_in[4];
    const float* W_B2   = (const float*)d_in[5];
    const float* W_pool = (const float*)d_in[6];
    const float* g_A1 = (const float*)d_in[7],  *b_A1 = (const float*)d_in[8];
    const float* g_A2 = (const float*)d_in[9],  *b_A2 = (const float*)d_in[10];
    const float* g_B1 = (const float*)d_in[11], *b_B1 = (const float*)d_in[12];
    const float* g_B2 = (const float*)d_in[13], *b_B2 = (const float*)d_in[14];

    char* p = (char*)d_ws;
    float* m     = (float*)p; p += (size_t)SP*4;
    float* omask = (float*)p; p += (size_t)OSP*4;
    float* statsN= (float*)p; p += 4*NSC*128*4;
    float* scsh  = (float*)p; p += 4*128*4;
    float* nactN = (float*)p; p += NSC*4;
    int*   flag  = (int*)p;   p += 4;
    p += 252;
    unsigned short* WtA1 = (unsigned short*)p; p += 288*64*2;
    unsigned short* WtA2 = (unsigned short*)p; p += 576*64*2;
    unsigned short* WtB1 = (unsigned short*)p; p += 288*64*2;
    unsigned short* WtB2 = (unsigned short*)p; p += 576*64*2;
    unsigned short* WtP  = (unsigned short*)p; p += 1728*64*2;
    unsigned short* X = (unsigned short*)p; p += (size_t)SP*32*2;
    unsigned short* P = (unsigned short*)p; p += (size_t)SP*64*2;
    unsigned short* Q = (unsigned short*)p; p += (size_t)SP*64*2;
    unsigned short* R = (unsigned short*)p; p += (size_t)SP*64*2;
    unsigned short* S = (unsigned short*)p; p += (size_t)SP*64*2;

    float* down = (float*)d_out;                 // [64][OSP]
    float* resf = down + (size_t)CO*OSP;         // [64][SP]

    const int shmP = 27*34*80;                   // 73440
    hipFuncSetAttribute((const void*)&mpool5, hipFuncAttributeMaxDynamicSharedMemorySize, shmP);

    hipMemsetAsync(statsN, 0, (4*NSC*128 + 4*128 + NSC)*4 + 4, stream);
    k_detect<<<256, 256, 0, stream>>>((const unsigned char*)mraw, flag);
    k_mask<<<SP/256, 256, 0, stream>>>(mraw, flag, m, nactN);
    k_wprep_all<<<864, 256, 0, stream>>>(W_A1, W_A2, W_B1, W_B2, W_pool,
                                         WtA1, WtA2, WtB1, WtB2, WtP);
    k_prep_x<<<SP/64, 256, 0, stream>>>(x, m, X, omask);

    float* SA1 = statsN + 0*NSC*128;
    float* SA2 = statsN + 1*NSC*128;
    float* SB1 = statsN + 2*NSC*128;
    float* SB2 = statsN + 3*NSC*128;

    // stage 1: A1 (KIND0, X->P) + B1 (KIND1, X->Q)
    mconv_dual<32,false,0,1><<<6400, 256, 0, stream>>>(
        X, WtA1, nullptr, P, SA1,
        X, WtB1, nullptr, Q, SB1, nullptr, m);
    k_finalize2<<<2, 64, 0, stream>>>(SA1, g_A1, b_A1, scsh + 0,
                                      SB1, g_B1, b_B1, scsh + 256, nactN);
    // stage 2: A2 (KIND1, P->R) + B2 (KIND0, Q->S)
    mconv_dual<64,true,1,0><<<6400, 256, 0, stream>>>(
        P, WtA2, scsh + 0,   R, SA2,
        Q, WtB2, scsh + 256, S, SB2, m, m);
    k_finalize2<<<2, 64, 0, stream>>>(SA2, g_A2, b_A2, scsh + 128,
                                      SB2, g_B2, b_B2, scsh + 384, nactN);
    // res_B combine -> Q (bf16 for pool) + resf (f32 output)
    k_resB<<<SP/64, 256, 0, stream>>>(R, S, scsh + 128, scsh + 384, m, Q, resf);
    // pool
    mpool5<<<1600, 256, shmP, stream>>>(Q, WtP, omask, down);
}